// Round 1
// baseline (1826.753 us; speedup 1.0000x reference)
//
#include <hip/hip_runtime.h>
#include <math.h>

// dims
#define B_ 2
#define S_ 256
#define CN_ 128
#define P_ 16
#define D_ 512
#define DI_ 1024
#define DS_ 16
#define DC_ 4
#define DT_ 32
#define NB_ 4
#define L_ 16
#define EPS_ 1e-5f

__device__ __forceinline__ float silu_f(float x) { return x / (1.f + __expf(-x)); }

// ---------------------------------------------------------------------------
// Embed: h[b,c,l,d] = sum_p x[b, l*16+p, c] * emb_w[d,p] + emb_b[d]
// grid: B*CN*L blocks (bid = bc*L + l), 256 threads
// ---------------------------------------------------------------------------
__global__ __launch_bounds__(256) void embed_kernel(
    const float* __restrict__ x, const float* __restrict__ emb_w,
    const float* __restrict__ emb_b, float* __restrict__ h)
{
    int bid = blockIdx.x;          // bc*L + l
    int l   = bid & (L_ - 1);
    int bc  = bid >> 4;
    int b   = bc >> 7;             // CN = 128
    int c   = bc & 127;
    __shared__ float xp[P_];
    int tid = threadIdx.x;
    if (tid < P_) xp[tid] = x[(size_t)(b * S_ + l * P_ + tid) * CN_ + c];
    __syncthreads();
    for (int dd = tid; dd < D_; dd += 256) {
        float acc = emb_b[dd];
#pragma unroll
        for (int p = 0; p < P_; ++p) acc += xp[p] * emb_w[dd * P_ + p];
        h[(size_t)bid * D_ + dd] = acc;
    }
}

// ---------------------------------------------------------------------------
// Generic f32 NT GEMM: C[m,n] = sum_k A[m,K]*W[n,K] (+ bias[n])
// 128x128 tile, BK=8, 256 threads, 8x8 per thread, k-major LDS (pad 132).
// Requires: M % 128 == 0, K % 8 == 0, N % 4 == 0. N may be < gridDim.y*128
// (guarded). Pointers 16B aligned.
// ---------------------------------------------------------------------------
__global__ __launch_bounds__(256) void gemm_nt128(
    const float* __restrict__ A, const float* __restrict__ W,
    const float* __restrict__ bias, float* __restrict__ C,
    int M, int N, int K)
{
    __shared__ float As[8][132];
    __shared__ float Ws[8][132];
    const int tid = threadIdx.x;
    const int tx = tid & 15, ty = tid >> 4;
    const int m0 = blockIdx.x * 128, n0 = blockIdx.y * 128;
    const int lm = tid >> 1;          // 0..127
    const int lk = (tid & 1) * 4;     // 0 or 4
    float acc[8][8] = {};
    const float* Aptr = A + (size_t)(m0 + lm) * K + lk;
    const float* Wptr = W + (size_t)(n0 + lm) * K + lk;
    const bool wvalid = (n0 + lm) < N;

    for (int k0 = 0; k0 < K; k0 += 8) {
        float4 a4 = *(const float4*)(Aptr + k0);
        float4 w4 = wvalid ? *(const float4*)(Wptr + k0) : make_float4(0.f, 0.f, 0.f, 0.f);
        __syncthreads();
        As[lk + 0][lm] = a4.x; As[lk + 1][lm] = a4.y; As[lk + 2][lm] = a4.z; As[lk + 3][lm] = a4.w;
        Ws[lk + 0][lm] = w4.x; Ws[lk + 1][lm] = w4.y; Ws[lk + 2][lm] = w4.z; Ws[lk + 3][lm] = w4.w;
        __syncthreads();
#pragma unroll
        for (int k = 0; k < 8; ++k) {
            float4 a0 = *(const float4*)&As[k][ty * 8];
            float4 a1 = *(const float4*)&As[k][ty * 8 + 4];
            float4 b0 = *(const float4*)&Ws[k][tx * 8];
            float4 b1 = *(const float4*)&Ws[k][tx * 8 + 4];
            float av[8] = {a0.x, a0.y, a0.z, a0.w, a1.x, a1.y, a1.z, a1.w};
            float bv[8] = {b0.x, b0.y, b0.z, b0.w, b1.x, b1.y, b1.z, b1.w};
#pragma unroll
            for (int i = 0; i < 8; ++i)
#pragma unroll
                for (int j = 0; j < 8; ++j)
                    acc[i][j] += av[i] * bv[j];
        }
    }

#pragma unroll
    for (int i = 0; i < 8; ++i) {
        int m = m0 + ty * 8 + i;
#pragma unroll
        for (int jq = 0; jq < 2; ++jq) {
            int n = n0 + tx * 8 + jq * 4;
            if (n < N) {
                float4 bq = bias ? *(const float4*)&bias[n] : make_float4(0.f, 0.f, 0.f, 0.f);
                float4 v;
                v.x = acc[i][jq * 4 + 0] + bq.x;
                v.y = acc[i][jq * 4 + 1] + bq.y;
                v.z = acc[i][jq * 4 + 2] + bq.z;
                v.w = acc[i][jq * 4 + 3] + bq.w;
                *(float4*)&C[(size_t)m * N + n] = v;
            }
        }
    }
}

// ---------------------------------------------------------------------------
// Causal depthwise conv (DC=4) over l + bias + silu.
// xs = xr[:, 0:DI]; out xc[bc,l,e]. idx = ((bc*L)+l)*DI + e
// ---------------------------------------------------------------------------
__global__ __launch_bounds__(256) void conv_silu_kernel(
    const float* __restrict__ xr, const float* __restrict__ conv_w,
    const float* __restrict__ conv_b, float* __restrict__ xc)
{
    int idx = blockIdx.x * 256 + threadIdx.x;
    int e = idx & (DI_ - 1);
    int l = (idx >> 10) & (L_ - 1);
    int bc = idx >> 14;
    float4 w = *(const float4*)&conv_w[e * DC_];
    const float* xs = xr + (size_t)bc * L_ * (2 * DI_) + e;
    float acc = conv_b[e];
    if (l >= 3) acc += w.x * xs[(size_t)(l - 3) * (2 * DI_)];
    if (l >= 2) acc += w.y * xs[(size_t)(l - 2) * (2 * DI_)];
    if (l >= 1) acc += w.z * xs[(size_t)(l - 1) * (2 * DI_)];
    acc += w.w * xs[(size_t)l * (2 * DI_)];
    xc[idx] = silu_f(acc);
}

// ---------------------------------------------------------------------------
// Selective scan, fused dt-projection + softplus + epilogue.
// One block per (b,c), 1024 threads (one per d). y written in place over xc.
// ---------------------------------------------------------------------------
__global__ __launch_bounds__(1024) void scan_kernel(
    const float* __restrict__ dbc, const float* __restrict__ xr,
    const float* __restrict__ dt_w, const float* __restrict__ dt_b,
    const float* __restrict__ A_log, const float* __restrict__ Dp,
    float* __restrict__ xc)
{
    int bc = blockIdx.x;
    int d = threadIdx.x;
    float dtw[DT_];
#pragma unroll
    for (int r = 0; r < DT_; ++r) dtw[r] = dt_w[d * DT_ + r];
    float Arow[DS_];
#pragma unroll
    for (int s = 0; s < DS_; ++s) Arow[s] = -__expf(A_log[d * DS_ + s]);
    float dtb = dt_b[d];
    float Dpd = Dp[d];
    float st[DS_];
#pragma unroll
    for (int s = 0; s < DS_; ++s) st[s] = 0.f;
    __shared__ float row[DT_ + 2 * DS_];

    for (int l = 0; l < L_; ++l) {
        __syncthreads();
        if (d < (DT_ + 2 * DS_)) row[d] = dbc[(size_t)(bc * L_ + l) * 64 + d];
        __syncthreads();
        float din = dtb;
#pragma unroll
        for (int r = 0; r < DT_; ++r) din += row[r] * dtw[r];
        float dt = (din > 20.f) ? din : __logf(1.f + __expf(din));
        size_t off = (size_t)(bc * L_ + l);
        float u = xc[off * DI_ + d];
        float du = dt * u;
        float y = 0.f;
#pragma unroll
        for (int s = 0; s < DS_; ++s) {
            float dA = __expf(dt * Arow[s]);
            st[s] = dA * st[s] + du * row[DT_ + s];
            y += st[s] * row[DT_ + DS_ + s];
        }
        float res = xr[off * (2 * DI_) + DI_ + d];
        xc[off * DI_ + d] = (y + Dpd * u) * silu_f(res);
    }
}

// ---------------------------------------------------------------------------
// Residual add + joint LayerNorm over (L,D)=8192 per (b,c). In-place on h.
// Two-pass mean/var for accuracy. One block per (b,c), 256 threads.
// ---------------------------------------------------------------------------
__global__ __launch_bounds__(256) void ln_kernel(
    float* __restrict__ h, const float* __restrict__ upd,
    const float* __restrict__ ln_w, const float* __restrict__ ln_b)
{
    int bc = blockIdx.x;
    int tid = threadIdx.x;
    __shared__ float vbuf[L_ * D_];   // 32 KiB
    __shared__ float ps[4];
    __shared__ float mu_s, rstd_s;

    float s = 0.f;
    for (int j = tid; j < L_ * D_; j += 256) {
        float v = h[(size_t)bc * (L_ * D_) + j] + upd[(size_t)bc * (L_ * D_) + j];
        vbuf[j] = v;
        s += v;
    }
#pragma unroll
    for (int o = 32; o > 0; o >>= 1) s += __shfl_down(s, o);
    if ((tid & 63) == 0) ps[tid >> 6] = s;
    __syncthreads();
    if (tid == 0) mu_s = (ps[0] + ps[1] + ps[2] + ps[3]) * (1.f / (L_ * D_));
    __syncthreads();
    float mu = mu_s;

    float s2 = 0.f;
    for (int j = tid; j < L_ * D_; j += 256) {
        float v = vbuf[j] - mu;
        s2 += v * v;
    }
#pragma unroll
    for (int o = 32; o > 0; o >>= 1) s2 += __shfl_down(s2, o);
    if ((tid & 63) == 0) ps[tid >> 6] = s2;
    __syncthreads();
    if (tid == 0) rstd_s = rsqrtf((ps[0] + ps[1] + ps[2] + ps[3]) * (1.f / (L_ * D_)) + EPS_);
    __syncthreads();
    float rstd = rstd_s;

    for (int j = tid; j < L_ * D_; j += 256) {
        h[(size_t)bc * (L_ * D_) + j] = (vbuf[j] - mu) * rstd * ln_w[j] + ln_b[j];
    }
}

// ---------------------------------------------------------------------------
// Head GEMM split-K: part[ks, m, s] = sum_{k in slice} hid[m,k]*step_w[s,k]
// grid (4,4,16): 64x64 tiles, K-slice of 512. 256 threads, 4x4 per thread.
// ---------------------------------------------------------------------------
__global__ __launch_bounds__(256) void head_gemm_kernel(
    const float* __restrict__ hid, const float* __restrict__ step_w,
    float* __restrict__ part)
{
    const int tid = threadIdx.x;
    const int tx = tid & 15, ty = tid >> 4;
    const int m0 = blockIdx.x * 64, n0 = blockIdx.y * 64;
    const int ks = blockIdx.z;
    const int kb = ks * 512;
    __shared__ float As[16][68];
    __shared__ float Ws[16][68];
    const int lm = tid >> 2;        // 0..63
    const int lk = (tid & 3) * 4;   // 0,4,8,12
    float acc[4][4] = {};

    for (int k0 = 0; k0 < 512; k0 += 16) {
        float4 a4 = *(const float4*)&hid[(size_t)(m0 + lm) * (L_ * D_) + kb + k0 + lk];
        float4 w4 = *(const float4*)&step_w[(size_t)(n0 + lm) * (L_ * D_) + kb + k0 + lk];
        __syncthreads();
        As[lk + 0][lm] = a4.x; As[lk + 1][lm] = a4.y; As[lk + 2][lm] = a4.z; As[lk + 3][lm] = a4.w;
        Ws[lk + 0][lm] = w4.x; Ws[lk + 1][lm] = w4.y; Ws[lk + 2][lm] = w4.z; Ws[lk + 3][lm] = w4.w;
        __syncthreads();
#pragma unroll
        for (int k = 0; k < 16; ++k) {
            float4 a = *(const float4*)&As[k][ty * 4];
            float4 b = *(const float4*)&Ws[k][tx * 4];
            float av[4] = {a.x, a.y, a.z, a.w};
            float bv[4] = {b.x, b.y, b.z, b.w};
#pragma unroll
            for (int i = 0; i < 4; ++i)
#pragma unroll
                for (int j = 0; j < 4; ++j)
                    acc[i][j] += av[i] * bv[j];
        }
    }
#pragma unroll
    for (int i = 0; i < 4; ++i) {
        *(float4*)&part[((size_t)ks * 256 + m0 + ty * 4 + i) * 256 + n0 + tx * 4] =
            make_float4(acc[i][0], acc[i][1], acc[i][2], acc[i][3]);
    }
}

// out[b,s,c] = step_b[s] + sum_ks part[ks, b*CN+c, s]
__global__ __launch_bounds__(256) void head_reduce_kernel(
    const float* __restrict__ part, const float* __restrict__ step_b,
    float* __restrict__ out)
{
    int j = blockIdx.x * 256 + threadIdx.x;  // (b*S+s)*CN + c
    int c = j & (CN_ - 1);
    int bs = j >> 7;
    int s = bs & (S_ - 1);
    int b = bs >> 8;
    int m = b * CN_ + c;
    float acc = step_b[s];
#pragma unroll
    for (int ks = 0; ks < 16; ++ks) acc += part[((size_t)ks * 256 + m) * 256 + s];
    out[j] = acc;
}

// ---------------------------------------------------------------------------
extern "C" void kernel_launch(void* const* d_in, const int* in_sizes, int n_in,
                              void* d_out, int out_size, void* d_ws, size_t ws_size,
                              hipStream_t stream)
{
    const float* x      = (const float*)d_in[0];
    const float* emb_w  = (const float*)d_in[1];
    const float* emb_b  = (const float*)d_in[2];
    const float* in_w   = (const float*)d_in[3];
    const float* in_b   = (const float*)d_in[4];
    const float* conv_w = (const float*)d_in[5];
    const float* conv_b = (const float*)d_in[6];
    const float* xproj_w= (const float*)d_in[7];
    const float* dt_w   = (const float*)d_in[8];
    const float* dt_b   = (const float*)d_in[9];
    const float* A_log  = (const float*)d_in[10];
    const float* Dp     = (const float*)d_in[11];
    const float* out_w  = (const float*)d_in[12];
    const float* out_b  = (const float*)d_in[13];
    const float* ln_w   = (const float*)d_in[14];
    const float* ln_b   = (const float*)d_in[15];
    const float* step_w = (const float*)d_in[16];
    const float* step_b = (const float*)d_in[17];
    float* out = (float*)d_out;

    char* ws = (char*)d_ws;
    // layout (bytes):
    //   h   : [4096, 512]  f32   @ 0          (8 MiB)
    //   xr  : [4096, 2048] f32   @ 8388608    (32 MiB)  (xs | res); reused as upd
    //   xc  : [4096, 1024] f32   @ 41943040   (16 MiB)  (y written in place)
    //   dbc : [4096, 64]   f32   @ 58720256   (1 MiB)
    //   hp  : [16,256,256] f32   @ 8388608    (4 MiB)   (aliases xr, used post-layers)
    float* h   = (float*)(ws);
    float* xr  = (float*)(ws + 8388608);
    float* xc  = (float*)(ws + 41943040);
    float* dbc = (float*)(ws + 58720256);
    float* hp  = (float*)(ws + 8388608);

    const int M = B_ * CN_ * L_;  // 4096

    embed_kernel<<<M, 256, 0, stream>>>(x, emb_w, emb_b, h);

    for (int i = 0; i < NB_; ++i) {
        // in-proj: [4096,512] x [2048,512]^T -> xr [4096,2048]
        gemm_nt128<<<dim3(M / 128, 2 * DI_ / 128), 256, 0, stream>>>(
            h, in_w + (size_t)i * 2 * DI_ * D_, in_b + (size_t)i * 2 * DI_, xr,
            M, 2 * DI_, D_);
        // depthwise conv + silu -> xc
        conv_silu_kernel<<<M * DI_ / 256, 256, 0, stream>>>(
            xr, conv_w + (size_t)i * DI_ * DC_, conv_b + (size_t)i * DI_, xc);
        // x-proj: [4096,1024] x [64,1024]^T -> dbc [4096,64]
        gemm_nt128<<<dim3(M / 128, 1), 256, 0, stream>>>(
            xc, xproj_w + (size_t)i * (DT_ + 2 * DS_) * DI_, nullptr, dbc,
            M, DT_ + 2 * DS_, DI_);
        // scan (fused dt proj + softplus + SSM + gate) : y -> xc (in place)
        scan_kernel<<<B_ * CN_, 1024, 0, stream>>>(
            dbc, xr, dt_w + (size_t)i * DI_ * DT_, dt_b + (size_t)i * DI_,
            A_log + (size_t)i * DI_ * DS_, Dp + (size_t)i * DI_, xc);
        // out-proj: [4096,1024] x [512,1024]^T -> upd (reuse xr)
        gemm_nt128<<<dim3(M / 128, D_ / 128), 256, 0, stream>>>(
            xc, out_w + (size_t)i * D_ * DI_, out_b + (size_t)i * D_, xr,
            M, D_, DI_);
        // residual + LayerNorm over (L,D), in place on h
        ln_kernel<<<B_ * CN_, 256, 0, stream>>>(
            h, xr, ln_w + (size_t)i * L_ * D_, ln_b + (size_t)i * L_ * D_);
    }

    // head: split-K GEMM then reduce + bias + transpose store
    head_gemm_kernel<<<dim3(4, 4, 16), 256, 0, stream>>>(h, step_w, hp);
    head_reduce_kernel<<<(B_ * S_ * CN_) / 256, 256, 0, stream>>>(hp, step_b, out);
}

// Round 2
// 596.541 us; speedup vs baseline: 3.0622x; 3.0622x over previous
//
#include <hip/hip_runtime.h>
#include <math.h>

// dims
#define B_ 2
#define S_ 256
#define CN_ 128
#define P_ 16
#define D_ 512
#define DI_ 1024
#define DS_ 16
#define DC_ 4
#define DT_ 32
#define NB_ 4
#define L_ 16
#define EPS_ 1e-5f

typedef unsigned short u16;
typedef __bf16 bf16x8 __attribute__((ext_vector_type(8)));
typedef float f32x4 __attribute__((ext_vector_type(4)));
typedef u16 u16x8 __attribute__((ext_vector_type(8)));

__device__ __forceinline__ float silu_f(float x) { return x / (1.f + __expf(-x)); }

__device__ __forceinline__ u16 f2bf(float f) {
    union { float f; unsigned u; } v; v.f = f;
    return (u16)((v.u + 0x7fffu + ((v.u >> 16) & 1u)) >> 16);
}

#define ASYNC_CP(gsrc, ldst)                                                        \
    __builtin_amdgcn_global_load_lds(                                               \
        (const __attribute__((address_space(1))) void*)(gsrc),                      \
        (__attribute__((address_space(3))) void*)(ldst), 16, 0, 0)

// ---------------------------------------------------------------------------
// f32 -> bf16 convert (n multiple of 2048)
// ---------------------------------------------------------------------------
__global__ __launch_bounds__(256) void cvt_bf16(
    const float* __restrict__ in, u16* __restrict__ out, int n)
{
    int i = (blockIdx.x * 256 + threadIdx.x) * 8;
    float4 a = *(const float4*)(in + i);
    float4 b = *(const float4*)(in + i + 4);
    u16x8 o;
    o[0] = f2bf(a.x); o[1] = f2bf(a.y); o[2] = f2bf(a.z); o[3] = f2bf(a.w);
    o[4] = f2bf(b.x); o[5] = f2bf(b.y); o[6] = f2bf(b.z); o[7] = f2bf(b.w);
    *(u16x8*)(out + i) = o;
}

// ---------------------------------------------------------------------------
// Embed: h[b,c,l,d] = sum_p x[b, l*16+p, c] * emb_w[d,p] + emb_b[d]
// also emits bf16 copy. grid: B*CN*L blocks, 256 threads
// ---------------------------------------------------------------------------
__global__ __launch_bounds__(256) void embed_kernel(
    const float* __restrict__ x, const float* __restrict__ emb_w,
    const float* __restrict__ emb_b, float* __restrict__ h, u16* __restrict__ hb)
{
    int bid = blockIdx.x;          // bc*L + l
    int l   = bid & (L_ - 1);
    int bc  = bid >> 4;
    int b   = bc >> 7;
    int c   = bc & 127;
    __shared__ float xp[P_];
    int tid = threadIdx.x;
    if (tid < P_) xp[tid] = x[(size_t)(b * S_ + l * P_ + tid) * CN_ + c];
    __syncthreads();
    for (int dd = tid; dd < D_; dd += 256) {
        float acc = emb_b[dd];
#pragma unroll
        for (int p = 0; p < P_; ++p) acc += xp[p] * emb_w[dd * P_ + p];
        h[(size_t)bid * D_ + dd] = acc;
        hb[(size_t)bid * D_ + dd] = f2bf(acc);
    }
}

// ---------------------------------------------------------------------------
// bf16 MFMA NT GEMM: C[m,n] = sum_k A[m,k]*W[n,k] (+ bias[n])
// 128x128 tile, BK=32, 256 threads (4 waves, 2x2), 4x4 16x16x32 frags/wave.
// global_load_lds width-16 staging, linear LDS [128][32].
// M multiple of 128 (by grid.x); N guarded. blockIdx.z advances A/W by kzStep
// elements and C by czStep elements (split-K partials).
// ---------------------------------------------------------------------------
__global__ __launch_bounds__(256) void gemm_bf16(
    const u16* __restrict__ A, int lda,
    const u16* __restrict__ W, int ldw,
    const float* __restrict__ bias,
    float* __restrict__ C, int ldc,
    int N, int kIters, int kzStep, int czStep)
{
    __shared__ u16 As[128 * 32];
    __shared__ u16 Ws[128 * 32];
    const int tid  = threadIdx.x;
    const int lane = tid & 63;
    const int wv   = tid >> 6;
    const int wr   = wv >> 1, wc = wv & 1;
    const int m0 = blockIdx.x * 128, n0 = blockIdx.y * 128;

    A += (size_t)blockIdx.z * kzStep;
    W += (size_t)blockIdx.z * kzStep;
    C += (size_t)blockIdx.z * czStep;

    // staging source pointers (thread t covers LDS linear elems t*8..t*8+7)
    const int srow = tid >> 2, scol = (tid & 3) * 8;
    const u16* Ag0 = A + (size_t)(m0 + srow) * lda + scol;
    const u16* Ag1 = Ag0 + (size_t)64 * lda;
    int wrow0 = n0 + srow;      if (wrow0 > N - 1) wrow0 = N - 1;
    int wrow1 = n0 + 64 + srow; if (wrow1 > N - 1) wrow1 = N - 1;
    const u16* Wg0 = W + (size_t)wrow0 * ldw + scol;
    const u16* Wg1 = W + (size_t)wrow1 * ldw + scol;
    // wave-uniform LDS dests (lane l lands at base + l*16B)
    u16* AsD0 = As + wv * 512;
    u16* AsD1 = As + 2048 + wv * 512;
    u16* WsD0 = Ws + wv * 512;
    u16* WsD1 = Ws + 2048 + wv * 512;

    const int frow = lane & 15;
    const int fk   = (lane >> 4) * 8;

    f32x4 acc[4][4] = {};

    for (int kt = 0; kt < kIters; ++kt) {
        ASYNC_CP(Ag0, AsD0);
        ASYNC_CP(Ag1, AsD1);
        ASYNC_CP(Wg0, WsD0);
        ASYNC_CP(Wg1, WsD1);
        Ag0 += 32; Ag1 += 32; Wg0 += 32; Wg1 += 32;
        __syncthreads();   // compiler drains vmcnt before s_barrier

        bf16x8 af[4], bf[4];
#pragma unroll
        for (int m = 0; m < 4; ++m)
            af[m] = *(const bf16x8*)&As[(wr * 64 + m * 16 + frow) * 32 + fk];
#pragma unroll
        for (int n = 0; n < 4; ++n)
            bf[n] = *(const bf16x8*)&Ws[(wc * 64 + n * 16 + frow) * 32 + fk];
#pragma unroll
        for (int m = 0; m < 4; ++m)
#pragma unroll
            for (int n = 0; n < 4; ++n)
                acc[m][n] = __builtin_amdgcn_mfma_f32_16x16x32_bf16(
                    af[m], bf[n], acc[m][n], 0, 0, 0);
        __syncthreads();   // LDS reads done before next-iter staging
    }

    // epilogue: C/D mapping col=lane&15, row=(lane>>4)*4+j
#pragma unroll
    for (int n = 0; n < 4; ++n) {
        int col = n0 + wc * 64 + n * 16 + (lane & 15);
        if (col < N) {
            float bv = bias ? bias[col] : 0.f;
#pragma unroll
            for (int m = 0; m < 4; ++m) {
                int rbase = m0 + wr * 64 + m * 16 + (lane >> 4) * 4;
#pragma unroll
                for (int j = 0; j < 4; ++j)
                    C[(size_t)(rbase + j) * ldc + col] = acc[m][n][j] + bv;
            }
        }
    }
}

// ---------------------------------------------------------------------------
// Causal depthwise conv (DC=4) + bias + silu; emits f32 and bf16.
// ---------------------------------------------------------------------------
__global__ __launch_bounds__(256) void conv_silu_kernel(
    const float* __restrict__ xr, const float* __restrict__ conv_w,
    const float* __restrict__ conv_b, float* __restrict__ xc,
    u16* __restrict__ xcb)
{
    int idx = blockIdx.x * 256 + threadIdx.x;
    int e = idx & (DI_ - 1);
    int l = (idx >> 10) & (L_ - 1);
    int bc = idx >> 14;
    float4 w = *(const float4*)&conv_w[e * DC_];
    const float* xs = xr + (size_t)bc * L_ * (2 * DI_) + e;
    float acc = conv_b[e];
    if (l >= 3) acc += w.x * xs[(size_t)(l - 3) * (2 * DI_)];
    if (l >= 2) acc += w.y * xs[(size_t)(l - 2) * (2 * DI_)];
    if (l >= 1) acc += w.z * xs[(size_t)(l - 1) * (2 * DI_)];
    acc += w.w * xs[(size_t)l * (2 * DI_)];
    float v = silu_f(acc);
    xc[idx] = v;
    xcb[idx] = f2bf(v);
}

// ---------------------------------------------------------------------------
// Selective scan; writes gated y as bf16 (feeds out-proj).
// ---------------------------------------------------------------------------
__global__ __launch_bounds__(1024) void scan_kernel(
    const float* __restrict__ dbc, const float* __restrict__ xr,
    const float* __restrict__ dt_w, const float* __restrict__ dt_b,
    const float* __restrict__ A_log, const float* __restrict__ Dp,
    const float* __restrict__ xc, u16* __restrict__ yb)
{
    int bc = blockIdx.x;
    int d = threadIdx.x;
    float dtw[DT_];
#pragma unroll
    for (int r = 0; r < DT_; ++r) dtw[r] = dt_w[d * DT_ + r];
    float Arow[DS_];
#pragma unroll
    for (int s = 0; s < DS_; ++s) Arow[s] = -__expf(A_log[d * DS_ + s]);
    float dtb = dt_b[d];
    float Dpd = Dp[d];
    float st[DS_];
#pragma unroll
    for (int s = 0; s < DS_; ++s) st[s] = 0.f;
    __shared__ float row[DT_ + 2 * DS_];

    for (int l = 0; l < L_; ++l) {
        __syncthreads();
        if (d < (DT_ + 2 * DS_)) row[d] = dbc[(size_t)(bc * L_ + l) * 64 + d];
        __syncthreads();
        float din = dtb;
#pragma unroll
        for (int r = 0; r < DT_; ++r) din += row[r] * dtw[r];
        float dt = (din > 20.f) ? din : __logf(1.f + __expf(din));
        size_t off = (size_t)(bc * L_ + l);
        float u = xc[off * DI_ + d];
        float du = dt * u;
        float y = 0.f;
#pragma unroll
        for (int s = 0; s < DS_; ++s) {
            float dA = __expf(dt * Arow[s]);
            st[s] = dA * st[s] + du * row[DT_ + s];
            y += st[s] * row[DT_ + DS_ + s];
        }
        float res = xr[off * (2 * DI_) + DI_ + d];
        yb[off * DI_ + d] = f2bf((y + Dpd * u) * silu_f(res));
    }
}

// ---------------------------------------------------------------------------
// Residual add + joint LayerNorm over (L,D)=8192 per (b,c). In-place on h,
// also emits bf16 copy. One block per (b,c), 256 threads.
// ---------------------------------------------------------------------------
__global__ __launch_bounds__(256) void ln_kernel(
    float* __restrict__ h, const float* __restrict__ upd,
    const float* __restrict__ ln_w, const float* __restrict__ ln_b,
    u16* __restrict__ hb)
{
    int bc = blockIdx.x;
    int tid = threadIdx.x;
    __shared__ float vbuf[L_ * D_];   // 32 KiB
    __shared__ float ps[4];
    __shared__ float mu_s, rstd_s;

    float s = 0.f;
    for (int j = tid; j < L_ * D_; j += 256) {
        float v = h[(size_t)bc * (L_ * D_) + j] + upd[(size_t)bc * (L_ * D_) + j];
        vbuf[j] = v;
        s += v;
    }
#pragma unroll
    for (int o = 32; o > 0; o >>= 1) s += __shfl_down(s, o);
    if ((tid & 63) == 0) ps[tid >> 6] = s;
    __syncthreads();
    if (tid == 0) mu_s = (ps[0] + ps[1] + ps[2] + ps[3]) * (1.f / (L_ * D_));
    __syncthreads();
    float mu = mu_s;

    float s2 = 0.f;
    for (int j = tid; j < L_ * D_; j += 256) {
        float v = vbuf[j] - mu;
        s2 += v * v;
    }
#pragma unroll
    for (int o = 32; o > 0; o >>= 1) s2 += __shfl_down(s2, o);
    if ((tid & 63) == 0) ps[tid >> 6] = s2;
    __syncthreads();
    if (tid == 0) rstd_s = rsqrtf((ps[0] + ps[1] + ps[2] + ps[3]) * (1.f / (L_ * D_)) + EPS_);
    __syncthreads();
    float rstd = rstd_s;

    for (int j = tid; j < L_ * D_; j += 256) {
        float v = (vbuf[j] - mu) * rstd * ln_w[j] + ln_b[j];
        h[(size_t)bc * (L_ * D_) + j] = v;
        hb[(size_t)bc * (L_ * D_) + j] = f2bf(v);
    }
}

// out[b,s,c] = step_b[s] + sum_ks part[ks, b*CN+c, s]   (32 slices)
__global__ __launch_bounds__(256) void head_reduce_kernel(
    const float* __restrict__ part, const float* __restrict__ step_b,
    float* __restrict__ out)
{
    int j = blockIdx.x * 256 + threadIdx.x;  // (b*S+s)*CN + c
    int c = j & (CN_ - 1);
    int bs = j >> 7;
    int s = bs & (S_ - 1);
    int b = bs >> 8;
    int m = b * CN_ + c;
    float acc = step_b[s];
#pragma unroll
    for (int ks = 0; ks < 32; ++ks) acc += part[((size_t)ks * 256 + m) * 256 + s];
    out[j] = acc;
}

// ---------------------------------------------------------------------------
extern "C" void kernel_launch(void* const* d_in, const int* in_sizes, int n_in,
                              void* d_out, int out_size, void* d_ws, size_t ws_size,
                              hipStream_t stream)
{
    const float* x      = (const float*)d_in[0];
    const float* emb_w  = (const float*)d_in[1];
    const float* emb_b  = (const float*)d_in[2];
    const float* in_w   = (const float*)d_in[3];
    const float* in_b   = (const float*)d_in[4];
    const float* conv_w = (const float*)d_in[5];
    const float* conv_b = (const float*)d_in[6];
    const float* xproj_w= (const float*)d_in[7];
    const float* dt_w   = (const float*)d_in[8];
    const float* dt_b   = (const float*)d_in[9];
    const float* A_log  = (const float*)d_in[10];
    const float* Dp     = (const float*)d_in[11];
    const float* out_w  = (const float*)d_in[12];
    const float* out_b  = (const float*)d_in[13];
    const float* ln_w   = (const float*)d_in[14];
    const float* ln_b   = (const float*)d_in[15];
    const float* step_w = (const float*)d_in[16];
    const float* step_b = (const float*)d_in[17];
    float* out = (float*)d_out;

    char* ws = (char*)d_ws;
    // workspace layout (bytes)
    float* h     = (float*)(ws);                    //  8 MiB  [4096,512]
    float* xr    = (float*)(ws + 8388608);          // 32 MiB  [4096,2048]; upd aliases
    float* xc    = (float*)(ws + 41943040);         // 16 MiB  [4096,1024]
    float* dbc   = (float*)(ws + 58720256);         //  1 MiB  [4096,64]
    u16*   hb    = (u16*)  (ws + 59768832);         //  4 MiB  [4096,512] bf16
    u16*   xcb   = (u16*)  (ws + 63963136);         //  8 MiB  [4096,1024] bf16; y aliases
    u16*   in_wb = (u16*)  (ws + 72351744);         //  8 MiB
    u16*   out_wb= (u16*)  (ws + 80740352);         //  4 MiB
    u16*   xp_wb = (u16*)  (ws + 84934656);         //  0.5 MiB
    u16*   st_wb = (u16*)  (ws + 85458944);         //  4 MiB
    float* part  = (float*)(ws + 8388608);          //  8 MiB [32,256,256] aliases xr

    const int M = B_ * CN_ * L_;  // 4096

    // weight conversions (every call; deterministic)
    cvt_bf16<<<NB_ * 2 * DI_ * D_ / 2048, 256, 0, stream>>>(in_w, in_wb, NB_ * 2 * DI_ * D_);
    cvt_bf16<<<NB_ * D_ * DI_ / 2048, 256, 0, stream>>>(out_w, out_wb, NB_ * D_ * DI_);
    cvt_bf16<<<NB_ * 64 * DI_ / 2048, 256, 0, stream>>>(xproj_w, xp_wb, NB_ * 64 * DI_);
    cvt_bf16<<<S_ * D_ * L_ / 2048, 256, 0, stream>>>(step_w, st_wb, S_ * D_ * L_);

    embed_kernel<<<M, 256, 0, stream>>>(x, emb_w, emb_b, h, hb);

    for (int i = 0; i < NB_; ++i) {
        // in-proj: [4096,512]bf16 x [2048,512]bf16^T -> xr f32
        gemm_bf16<<<dim3(M / 128, 16), 256, 0, stream>>>(
            hb, D_, in_wb + (size_t)i * 2 * DI_ * D_, D_, in_b + (size_t)i * 2 * DI_,
            xr, 2 * DI_, 2 * DI_, D_ / 32, 0, 0);
        // conv + silu -> xc f32 + xcb bf16
        conv_silu_kernel<<<M * DI_ / 256, 256, 0, stream>>>(
            xr, conv_w + (size_t)i * DI_ * DC_, conv_b + (size_t)i * DI_, xc, xcb);
        // x-proj: [4096,1024] x [64,1024]^T -> dbc f32
        gemm_bf16<<<dim3(M / 128, 1), 256, 0, stream>>>(
            xcb, DI_, xp_wb + (size_t)i * 64 * DI_, DI_, nullptr,
            dbc, 64, 64, DI_ / 32, 0, 0);
        // scan: y (gated) -> xcb region as bf16
        scan_kernel<<<B_ * CN_, 1024, 0, stream>>>(
            dbc, xr, dt_w + (size_t)i * DI_ * DT_, dt_b + (size_t)i * DI_,
            A_log + (size_t)i * DI_ * DS_, Dp + (size_t)i * DI_, xc, xcb);
        // out-proj: [4096,1024] x [512,1024]^T -> upd f32 (aliases xr)
        gemm_bf16<<<dim3(M / 128, 4), 256, 0, stream>>>(
            xcb, DI_, out_wb + (size_t)i * D_ * DI_, DI_, out_b + (size_t)i * D_,
            xr, D_, D_, DI_ / 32, 0, 0);
        // residual + LayerNorm -> h f32 (in place) + hb bf16
        ln_kernel<<<B_ * CN_, 256, 0, stream>>>(
            h, xr, ln_w + (size_t)i * L_ * D_, ln_b + (size_t)i * L_ * D_, hb);
    }

    // head: split-K MFMA GEMM (hid [256,8192] = hb) + reduce/transpose
    gemm_bf16<<<dim3(2, 2, 32), 256, 0, stream>>>(
        hb, L_ * D_, st_wb, L_ * D_, nullptr,
        part, S_, S_, 8, 256, 256 * 256);
    head_reduce_kernel<<<(B_ * S_ * CN_) / 256, 256, 0, stream>>>(part, step_b, out);
}

// Round 3
// 413.968 us; speedup vs baseline: 4.4128x; 1.4410x over previous
//
#include <hip/hip_runtime.h>
#include <math.h>

// dims
#define B_ 2
#define S_ 256
#define CN_ 128
#define P_ 16
#define D_ 512
#define DI_ 1024
#define DS_ 16
#define DC_ 4
#define DT_ 32
#define NB_ 4
#define L_ 16
#define EPS_ 1e-5f

typedef unsigned short u16;
typedef __bf16 bf16x8 __attribute__((ext_vector_type(8)));
typedef float f32x4 __attribute__((ext_vector_type(4)));
typedef u16 u16x8 __attribute__((ext_vector_type(8)));
typedef u16 u16x4 __attribute__((ext_vector_type(4)));
typedef u16 u16x2 __attribute__((ext_vector_type(2)));

__device__ __forceinline__ float silu_f(float x) { return x / (1.f + __expf(-x)); }

__device__ __forceinline__ u16 f2bf(float f) {
    union { float f; unsigned u; } v; v.f = f;
    return (u16)((v.u + 0x7fffu + ((v.u >> 16) & 1u)) >> 16);
}
__device__ __forceinline__ float bf2f(u16 b) {
    union { unsigned u; float f; } v; v.u = ((unsigned)b) << 16; return v.f;
}

#define ASYNC_CP(gsrc, ldst)                                                        \
    __builtin_amdgcn_global_load_lds(                                               \
        (const __attribute__((address_space(1))) void*)(gsrc),                      \
        (__attribute__((address_space(3))) void*)(ldst), 16, 0, 0)

// ---------------------------------------------------------------------------
// Fused f32->bf16 weight convert. Segments: in_w(2048 blk), out_w(1024),
// xproj_w(128), step_w(1024). 8 elems/thread.
// ---------------------------------------------------------------------------
__global__ __launch_bounds__(256) void cvt_all(
    const float* __restrict__ in_w, const float* __restrict__ out_w,
    const float* __restrict__ xproj_w, const float* __restrict__ step_w,
    u16* __restrict__ in_wb, u16* __restrict__ out_wb,
    u16* __restrict__ xp_wb, u16* __restrict__ st_wb)
{
    int blk = blockIdx.x;
    const float* src; u16* dst; int base;
    if (blk < 2048)      { src = in_w;    dst = in_wb;  base = blk; }
    else if (blk < 3072) { src = out_w;   dst = out_wb; base = blk - 2048; }
    else if (blk < 3200) { src = xproj_w; dst = xp_wb;  base = blk - 3072; }
    else                 { src = step_w;  dst = st_wb;  base = blk - 3200; }
    int i = (base * 256 + threadIdx.x) * 8;
    float4 a = *(const float4*)(src + i);
    float4 b = *(const float4*)(src + i + 4);
    u16x8 o;
    o[0] = f2bf(a.x); o[1] = f2bf(a.y); o[2] = f2bf(a.z); o[3] = f2bf(a.w);
    o[4] = f2bf(b.x); o[5] = f2bf(b.y); o[6] = f2bf(b.z); o[7] = f2bf(b.w);
    *(u16x8*)(dst + i) = o;
}

// ---------------------------------------------------------------------------
// Embed: h[b,c,l,d] = sum_p x[b, l*16+p, c] * emb_w[d,p] + emb_b[d]
// ---------------------------------------------------------------------------
__global__ __launch_bounds__(256) void embed_kernel(
    const float* __restrict__ x, const float* __restrict__ emb_w,
    const float* __restrict__ emb_b, float* __restrict__ h, u16* __restrict__ hb)
{
    int bid = blockIdx.x;          // bc*L + l
    int l   = bid & (L_ - 1);
    int bc  = bid >> 4;
    int b   = bc >> 7;
    int c   = bc & 127;
    __shared__ float xp[P_];
    int tid = threadIdx.x;
    if (tid < P_) xp[tid] = x[(size_t)(b * S_ + l * P_ + tid) * CN_ + c];
    __syncthreads();
    for (int dd = tid; dd < D_; dd += 256) {
        float acc = emb_b[dd];
#pragma unroll
        for (int p = 0; p < P_; ++p) acc += xp[p] * emb_w[dd * P_ + p];
        h[(size_t)bid * D_ + dd] = acc;
        hb[(size_t)bid * D_ + dd] = f2bf(acc);
    }
}

// ---------------------------------------------------------------------------
// bf16 MFMA NT GEMM, 128x128 tile, BK=32, 4 waves, double-buffered LDS
// (2-phase prefetch: stage k+1 before compute k; one barrier per K-step).
// MODE 0: plain f32 C write (split-K via blockIdx.z, no bias).
// MODE 1: in-proj fused epilogue — C-tile -> LDS f32 [128][129]; for
//         blockIdx.y<8: +in_b, causal depthwise conv(DC=4)+conv_b, silu ->
//         xcb bf16; for y>=8: +in_b, silu -> sresb bf16.
// ---------------------------------------------------------------------------
template<int MODE>
__global__ __launch_bounds__(256) void gemm_bf16(
    const u16* __restrict__ A, int lda,
    const u16* __restrict__ W, int ldw,
    float* __restrict__ C, int ldc, int N,
    int kIters, int kzStep, int czStep,
    const float* __restrict__ in_b, const float* __restrict__ conv_w,
    const float* __restrict__ conv_b,
    u16* __restrict__ xcb, u16* __restrict__ sresb)
{
    constexpr int SMEM = (MODE == 1) ? (128 * 129 * 4) : 32768;
    __shared__ char smem[SMEM];
    u16* As = (u16*)smem;              // [2][4096] u16
    u16* Ws = (u16*)(smem + 16384);    // [2][4096] u16

    const int tid  = threadIdx.x;
    const int lane = tid & 63;
    const int wv   = tid >> 6;
    const int wr   = wv >> 1, wc = wv & 1;
    const int m0 = blockIdx.x * 128, n0 = blockIdx.y * 128;

    A += (size_t)blockIdx.z * kzStep;
    W += (size_t)blockIdx.z * kzStep;
    C += (size_t)blockIdx.z * czStep;

    const int srow = tid >> 2, scol = (tid & 3) * 8;
    const u16* Ag = A + (size_t)(m0 + srow) * lda + scol;
    int wrow0 = n0 + srow;      if (wrow0 > N - 1) wrow0 = N - 1;
    int wrow1 = n0 + 64 + srow; if (wrow1 > N - 1) wrow1 = N - 1;
    const u16* Wg0 = W + (size_t)wrow0 * ldw + scol;
    const u16* Wg1 = W + (size_t)wrow1 * ldw + scol;

    const int frow = lane & 15;
    const int fk   = (lane >> 4) * 8;

    f32x4 acc[4][4] = {};

    // prologue: stage K-step 0 into buf 0
    ASYNC_CP(Ag, As + wv * 512);
    ASYNC_CP(Ag + (size_t)64 * lda, As + 2048 + wv * 512);
    ASYNC_CP(Wg0, Ws + wv * 512);
    ASYNC_CP(Wg1, Ws + 2048 + wv * 512);
    __syncthreads();

    for (int kt = 0; kt < kIters; ++kt) {
        const int cur = (kt & 1) * 4096;
        const int nxt = 4096 - cur;
        if (kt + 1 < kIters) {
            const int ko = (kt + 1) * 32;
            ASYNC_CP(Ag + ko, As + nxt + wv * 512);
            ASYNC_CP(Ag + ko + (size_t)64 * lda, As + nxt + 2048 + wv * 512);
            ASYNC_CP(Wg0 + ko, Ws + nxt + wv * 512);
            ASYNC_CP(Wg1 + ko, Ws + nxt + 2048 + wv * 512);
        }
        bf16x8 af[4], bf[4];
#pragma unroll
        for (int m = 0; m < 4; ++m)
            af[m] = *(const bf16x8*)&As[cur + (wr * 64 + m * 16 + frow) * 32 + fk];
#pragma unroll
        for (int n = 0; n < 4; ++n)
            bf[n] = *(const bf16x8*)&Ws[cur + (wc * 64 + n * 16 + frow) * 32 + fk];
#pragma unroll
        for (int m = 0; m < 4; ++m)
#pragma unroll
            for (int n = 0; n < 4; ++n)
                acc[m][n] = __builtin_amdgcn_mfma_f32_16x16x32_bf16(
                    af[m], bf[n], acc[m][n], 0, 0, 0);
        __syncthreads();   // drains prefetch vmcnt + orders LDS reuse
    }

    if (MODE == 0) {
        // direct f32 write: col = lane&15 group, row = (lane>>4)*4+j
#pragma unroll
        for (int n = 0; n < 4; ++n) {
            int col = n0 + wc * 64 + n * 16 + (lane & 15);
            if (col < N) {
#pragma unroll
                for (int m = 0; m < 4; ++m) {
                    int rbase = m0 + wr * 64 + m * 16 + (lane >> 4) * 4;
#pragma unroll
                    for (int j = 0; j < 4; ++j)
                        C[(size_t)(rbase + j) * ldc + col] = acc[m][n][j];
                }
            }
        }
    } else {
        // stage C-tile to LDS f32 [128][129]
        float* tile = (float*)smem;
#pragma unroll
        for (int m = 0; m < 4; ++m) {
            int r = wr * 64 + m * 16 + (lane >> 4) * 4;
#pragma unroll
            for (int n = 0; n < 4; ++n) {
                int c = wc * 64 + n * 16 + (lane & 15);
#pragma unroll
                for (int j = 0; j < 4; ++j)
                    tile[(r + j) * 129 + c] = acc[m][n][j];
            }
        }
        __syncthreads();

        const bool isXs = (blockIdx.y < 8);
        const int cA = (tid * 2) & 127;        // two cols: cA, cA+1
        const int rb = tid >> 6;               // 0..3
        const float ib0 = in_b[n0 + cA];
        const float ib1 = in_b[n0 + cA + 1];
        if (isXs) {
            const int e0 = n0 + cA;            // n0 < 1024
            float4 w0 = *(const float4*)&conv_w[e0 * DC_];
            float4 w1 = *(const float4*)&conv_w[(e0 + 1) * DC_];
            float cb0 = conv_b[e0], cb1 = conv_b[e0 + 1];
            for (int it = 0; it < 32; ++it) {
                int r = it * 4 + rb;
                int l = r & 15;
                float c3a = tile[r * 129 + cA] + ib0;
                float c3b = tile[r * 129 + cA + 1] + ib1;
                float c2a = (l >= 1) ? tile[(r - 1) * 129 + cA] + ib0 : 0.f;
                float c2b = (l >= 1) ? tile[(r - 1) * 129 + cA + 1] + ib1 : 0.f;
                float c1a = (l >= 2) ? tile[(r - 2) * 129 + cA] + ib0 : 0.f;
                float c1b = (l >= 2) ? tile[(r - 2) * 129 + cA + 1] + ib1 : 0.f;
                float c0a = (l >= 3) ? tile[(r - 3) * 129 + cA] + ib0 : 0.f;
                float c0b = (l >= 3) ? tile[(r - 3) * 129 + cA + 1] + ib1 : 0.f;
                float va = cb0 + w0.x * c0a + w0.y * c1a + w0.z * c2a + w0.w * c3a;
                float vb = cb1 + w1.x * c0b + w1.y * c1b + w1.z * c2b + w1.w * c3b;
                u16x2 o; o[0] = f2bf(silu_f(va)); o[1] = f2bf(silu_f(vb));
                *(u16x2*)&xcb[(size_t)(m0 + r) * DI_ + e0] = o;
            }
        } else {
            const int e0 = n0 - 1024 + cA;
            for (int it = 0; it < 32; ++it) {
                int r = it * 4 + rb;
                float va = silu_f(tile[r * 129 + cA] + ib0);
                float vb = silu_f(tile[r * 129 + cA + 1] + ib1);
                u16x2 o; o[0] = f2bf(va); o[1] = f2bf(vb);
                *(u16x2*)&sresb[(size_t)(m0 + r) * DI_ + e0] = o;
            }
        }
    }
}

// ---------------------------------------------------------------------------
// Selective scan: fused dt-projection + softplus + SSM + gate.
// dbc is 2 split-K partials. u from xcb (bf16), gate from sresb (bf16).
// ---------------------------------------------------------------------------
__global__ __launch_bounds__(1024) void scan_kernel(
    const float* __restrict__ dbc, const u16* __restrict__ xcb,
    const u16* __restrict__ sresb,
    const float* __restrict__ dt_w, const float* __restrict__ dt_b,
    const float* __restrict__ A_log, const float* __restrict__ Dp,
    u16* __restrict__ yb)
{
    int bc = blockIdx.x;
    int d = threadIdx.x;
    float dtw[DT_];
#pragma unroll
    for (int r = 0; r < DT_; ++r) dtw[r] = dt_w[d * DT_ + r];
    float Arow[DS_];
#pragma unroll
    for (int s = 0; s < DS_; ++s) Arow[s] = -__expf(A_log[d * DS_ + s]);
    float dtb = dt_b[d];
    float Dpd = Dp[d];
    float st[DS_];
#pragma unroll
    for (int s = 0; s < DS_; ++s) st[s] = 0.f;
    __shared__ float row[DT_ + 2 * DS_];

    for (int l = 0; l < L_; ++l) {
        size_t off = (size_t)(bc * L_ + l);
        __syncthreads();
        if (d < 64) row[d] = dbc[off * 64 + d] + dbc[(size_t)4096 * 64 + off * 64 + d];
        __syncthreads();
        float din = dtb;
#pragma unroll
        for (int r = 0; r < DT_; ++r) din += row[r] * dtw[r];
        float dt = (din > 20.f) ? din : __logf(1.f + __expf(din));
        float u = bf2f(xcb[off * DI_ + d]);
        float du = dt * u;
        float y = 0.f;
#pragma unroll
        for (int s = 0; s < DS_; ++s) {
            float dA = __expf(dt * Arow[s]);
            st[s] = dA * st[s] + du * row[DT_ + s];
            y += st[s] * row[DT_ + DS_ + s];
        }
        float sres = bf2f(sresb[off * DI_ + d]);
        yb[off * DI_ + d] = f2bf((y + Dpd * u) * sres);
    }
}

// ---------------------------------------------------------------------------
// Residual add (h + upd0 + upd1 + out_b) + joint LayerNorm over (L,D)=8192.
// float4 throughout. One block per (b,c), 256 threads.
// ---------------------------------------------------------------------------
__global__ __launch_bounds__(256) void ln_kernel(
    float* __restrict__ h, const float* __restrict__ upd,
    const float* __restrict__ out_b,
    const float* __restrict__ ln_w, const float* __restrict__ ln_b,
    u16* __restrict__ hb)
{
    int bc = blockIdx.x;
    int tid = threadIdx.x;
    __shared__ float vbuf[L_ * D_];   // 32 KiB
    __shared__ float ps[4];
    __shared__ float mu_s, rstd_s;

    float4* vb4 = (float4*)vbuf;
    const float4* h4 = (const float4*)(h + (size_t)bc * 8192);
    const float4* u0 = (const float4*)(upd + (size_t)bc * 8192);
    const float4* u1 = (const float4*)(upd + (size_t)2097152 + (size_t)bc * 8192);
    const float4* ob = (const float4*)out_b;

    float s = 0.f;
    for (int j = tid; j < 2048; j += 256) {
        float4 v = h4[j], a = u0[j], b = u1[j], o = ob[j & 127];
        v.x += a.x + b.x + o.x; v.y += a.y + b.y + o.y;
        v.z += a.z + b.z + o.z; v.w += a.w + b.w + o.w;
        vb4[j] = v;
        s += v.x + v.y + v.z + v.w;
    }
#pragma unroll
    for (int o = 32; o > 0; o >>= 1) s += __shfl_down(s, o);
    if ((tid & 63) == 0) ps[tid >> 6] = s;
    __syncthreads();
    if (tid == 0) mu_s = (ps[0] + ps[1] + ps[2] + ps[3]) * (1.f / 8192.f);
    __syncthreads();
    float mu = mu_s;

    float s2 = 0.f;
    for (int j = tid; j < 8192; j += 256) {
        float v = vbuf[j] - mu;
        s2 += v * v;
    }
#pragma unroll
    for (int o = 32; o > 0; o >>= 1) s2 += __shfl_down(s2, o);
    if ((tid & 63) == 0) ps[tid >> 6] = s2;
    __syncthreads();
    if (tid == 0) rstd_s = rsqrtf((ps[0] + ps[1] + ps[2] + ps[3]) * (1.f / 8192.f) + EPS_);
    __syncthreads();
    float rstd = rstd_s;

    const float4* lw4 = (const float4*)ln_w;
    const float4* lb4 = (const float4*)ln_b;
    float4* ho4 = (float4*)(h + (size_t)bc * 8192);
    for (int j = tid; j < 2048; j += 256) {
        float4 v = vb4[j], w = lw4[j], b = lb4[j];
        v.x = (v.x - mu) * rstd * w.x + b.x;
        v.y = (v.y - mu) * rstd * w.y + b.y;
        v.z = (v.z - mu) * rstd * w.z + b.z;
        v.w = (v.w - mu) * rstd * w.w + b.w;
        ho4[j] = v;
        u16x4 ob16; ob16[0] = f2bf(v.x); ob16[1] = f2bf(v.y);
        ob16[2] = f2bf(v.z); ob16[3] = f2bf(v.w);
        *(u16x4*)&hb[(size_t)bc * 8192 + j * 4] = ob16;
    }
}

// out[b,s,c] = step_b[s] + sum_ks part[ks, b*CN+c, s]   (32 slices)
__global__ __launch_bounds__(256) void head_reduce_kernel(
    const float* __restrict__ part, const float* __restrict__ step_b,
    float* __restrict__ out)
{
    int j = blockIdx.x * 256 + threadIdx.x;  // (b*S+s)*CN + c
    int c = j & (CN_ - 1);
    int bs = j >> 7;
    int s = bs & (S_ - 1);
    int b = bs >> 8;
    int m = b * CN_ + c;
    float acc = step_b[s];
#pragma unroll
    for (int ks = 0; ks < 32; ++ks) acc += part[((size_t)ks * 256 + m) * 256 + s];
    out[j] = acc;
}

// ---------------------------------------------------------------------------
extern "C" void kernel_launch(void* const* d_in, const int* in_sizes, int n_in,
                              void* d_out, int out_size, void* d_ws, size_t ws_size,
                              hipStream_t stream)
{
    const float* x      = (const float*)d_in[0];
    const float* emb_w  = (const float*)d_in[1];
    const float* emb_b  = (const float*)d_in[2];
    const float* in_w   = (const float*)d_in[3];
    const float* in_b   = (const float*)d_in[4];
    const float* conv_w = (const float*)d_in[5];
    const float* conv_b = (const float*)d_in[6];
    const float* xproj_w= (const float*)d_in[7];
    const float* dt_w   = (const float*)d_in[8];
    const float* dt_b   = (const float*)d_in[9];
    const float* A_log  = (const float*)d_in[10];
    const float* Dp     = (const float*)d_in[11];
    const float* out_w  = (const float*)d_in[12];
    const float* out_b  = (const float*)d_in[13];
    const float* ln_w   = (const float*)d_in[14];
    const float* ln_b   = (const float*)d_in[15];
    const float* step_w = (const float*)d_in[16];
    const float* step_b = (const float*)d_in[17];
    float* out = (float*)d_out;

    char* ws = (char*)d_ws;
    float* h     = (float*)(ws);                    //  8 MiB [4096,512]
    u16*   hb    = (u16*)  (ws + 8388608);          //  4 MiB
    u16*   xcb   = (u16*)  (ws + 12582912);         //  8 MiB [4096,1024]
    u16*   sresb = (u16*)  (ws + 20971520);         //  8 MiB
    u16*   yb    = (u16*)  (ws + 29360128);         //  8 MiB
    float* dbc   = (float*)(ws + 37748736);         //  2 MiB [2][4096][64]
    float* upd   = (float*)(ws + 39845888);         // 16 MiB [2][4096][512]
    u16*   in_wb = (u16*)  (ws + 56623104);         //  8 MiB
    u16*   out_wb= (u16*)  (ws + 65011712);         //  4 MiB
    u16*   xp_wb = (u16*)  (ws + 69206016);         //  0.5 MiB
    u16*   st_wb = (u16*)  (ws + 69730304);         //  4 MiB
    float* part  = (float*)(ws + 73924608);         //  8 MiB [32,256,256]

    const int M = B_ * CN_ * L_;  // 4096

    cvt_all<<<4224, 256, 0, stream>>>(in_w, out_w, xproj_w, step_w,
                                      in_wb, out_wb, xp_wb, st_wb);
    embed_kernel<<<M, 256, 0, stream>>>(x, emb_w, emb_b, h, hb);

    for (int i = 0; i < NB_; ++i) {
        // in-proj + bias + causal conv + silu + res-silu (fused epilogue)
        gemm_bf16<1><<<dim3(M / 128, 16, 1), 256, 0, stream>>>(
            hb, D_, in_wb + (size_t)i * 2 * DI_ * D_, D_,
            nullptr, 0, 2 * DI_, D_ / 32, 0, 0,
            in_b + (size_t)i * 2 * DI_, conv_w + (size_t)i * DI_ * DC_,
            conv_b + (size_t)i * DI_, xcb, sresb);
        // x-proj split-K x2 -> dbc partials
        gemm_bf16<0><<<dim3(M / 128, 1, 2), 256, 0, stream>>>(
            xcb, DI_, xp_wb + (size_t)i * 64 * DI_, DI_,
            dbc, 64, 64, 16, 512, M * 64,
            nullptr, nullptr, nullptr, nullptr, nullptr);
        // scan: dt-proj + softplus + SSM + gate -> yb bf16
        scan_kernel<<<B_ * CN_, 1024, 0, stream>>>(
            dbc, xcb, sresb, dt_w + (size_t)i * DI_ * DT_, dt_b + (size_t)i * DI_,
            A_log + (size_t)i * DI_ * DS_, Dp + (size_t)i * DI_, yb);
        // out-proj split-K x2 -> upd partials
        gemm_bf16<0><<<dim3(M / 128, 4, 2), 256, 0, stream>>>(
            yb, DI_, out_wb + (size_t)i * D_ * DI_, DI_,
            upd, D_, D_, 16, 512, M * D_,
            nullptr, nullptr, nullptr, nullptr, nullptr);
        // residual (+out_b) + LayerNorm
        ln_kernel<<<B_ * CN_, 256, 0, stream>>>(
            h, upd, out_b + (size_t)i * D_,
            ln_w + (size_t)i * L_ * D_, ln_b + (size_t)i * L_ * D_, hb);
    }

    // head: split-K 32 MFMA GEMM + reduce/transpose
    gemm_bf16<0><<<dim3(2, 2, 32), 256, 0, stream>>>(
        hb, L_ * D_, st_wb, L_ * D_,
        part, S_, S_, 8, 256, 256 * 256,
        nullptr, nullptr, nullptr, nullptr, nullptr);
    head_reduce_kernel<<<(B_ * S_ * CN_) / 256, 256, 0, stream>>>(part, step_b, out);
}

// Round 4
// 374.627 us; speedup vs baseline: 4.8762x; 1.1050x over previous
//
#include <hip/hip_runtime.h>
#include <math.h>

// dims
#define B_ 2
#define S_ 256
#define CN_ 128
#define P_ 16
#define D_ 512
#define DI_ 1024
#define DS_ 16
#define DC_ 4
#define DT_ 32
#define NB_ 4
#define L_ 16
#define EPS_ 1e-5f

typedef unsigned short u16;
typedef __bf16 bf16x8 __attribute__((ext_vector_type(8)));
typedef float f32x4 __attribute__((ext_vector_type(4)));
typedef u16 u16x8 __attribute__((ext_vector_type(8)));
typedef u16 u16x4 __attribute__((ext_vector_type(4)));
typedef u16 u16x2 __attribute__((ext_vector_type(2)));

__device__ __forceinline__ float silu_f(float x) { return x / (1.f + __expf(-x)); }

__device__ __forceinline__ u16 f2bf(float f) {
    union { float f; unsigned u; } v; v.f = f;
    return (u16)((v.u + 0x7fffu + ((v.u >> 16) & 1u)) >> 16);
}
__device__ __forceinline__ float bf2f(u16 b) {
    union { unsigned u; float f; } v; v.u = ((unsigned)b) << 16; return v.f;
}

#define ASYNC_CP(gsrc, ldst)                                                        \
    __builtin_amdgcn_global_load_lds(                                               \
        (const __attribute__((address_space(1))) void*)(gsrc),                      \
        (__attribute__((address_space(3))) void*)(ldst), 16, 0, 0)

#define MFMA16(a, b, c) __builtin_amdgcn_mfma_f32_16x16x32_bf16((a), (b), (c), 0, 0, 0)

// ---------------------------------------------------------------------------
// Fused f32->bf16 weight convert. Segments: in_w(2048 blk), out_w(1024),
// xproj_w(128), step_w(1024), dt_w(64). 8 elems/thread.
// ---------------------------------------------------------------------------
__global__ __launch_bounds__(256) void cvt_all(
    const float* __restrict__ in_w, const float* __restrict__ out_w,
    const float* __restrict__ xproj_w, const float* __restrict__ step_w,
    const float* __restrict__ dt_w,
    u16* __restrict__ in_wb, u16* __restrict__ out_wb,
    u16* __restrict__ xp_wb, u16* __restrict__ st_wb, u16* __restrict__ dt_wb)
{
    int blk = blockIdx.x;
    const float* src; u16* dst; int base;
    if (blk < 2048)      { src = in_w;    dst = in_wb;  base = blk; }
    else if (blk < 3072) { src = out_w;   dst = out_wb; base = blk - 2048; }
    else if (blk < 3200) { src = xproj_w; dst = xp_wb;  base = blk - 3072; }
    else if (blk < 4224) { src = step_w;  dst = st_wb;  base = blk - 3200; }
    else                 { src = dt_w;    dst = dt_wb;  base = blk - 4224; }
    int i = (base * 256 + threadIdx.x) * 8;
    float4 a = *(const float4*)(src + i);
    float4 b = *(const float4*)(src + i + 4);
    u16x8 o;
    o[0] = f2bf(a.x); o[1] = f2bf(a.y); o[2] = f2bf(a.z); o[3] = f2bf(a.w);
    o[4] = f2bf(b.x); o[5] = f2bf(b.y); o[6] = f2bf(b.z); o[7] = f2bf(b.w);
    *(u16x8*)(dst + i) = o;
}

// ---------------------------------------------------------------------------
// Embed: h[b,c,l,d] = sum_p x[b, l*16+p, c] * emb_w[d,p] + emb_b[d]
// ---------------------------------------------------------------------------
__global__ __launch_bounds__(256) void embed_kernel(
    const float* __restrict__ x, const float* __restrict__ emb_w,
    const float* __restrict__ emb_b, float* __restrict__ h, u16* __restrict__ hb)
{
    int bid = blockIdx.x;          // bc*L + l
    int l   = bid & (L_ - 1);
    int bc  = bid >> 4;
    int b   = bc >> 7;
    int c   = bc & 127;
    __shared__ float xp[P_];
    int tid = threadIdx.x;
    if (tid < P_) xp[tid] = x[(size_t)(b * S_ + l * P_ + tid) * CN_ + c];
    __syncthreads();
    for (int dd = tid; dd < D_; dd += 256) {
        float acc = emb_b[dd];
#pragma unroll
        for (int p = 0; p < P_; ++p) acc += xp[p] * emb_w[dd * P_ + p];
        h[(size_t)bid * D_ + dd] = acc;
        hb[(size_t)bid * D_ + dd] = f2bf(acc);
    }
}

// ---------------------------------------------------------------------------
// bf16 MFMA NT GEMM, 128x128 tile, BK=32, 4 waves, double-buffered LDS.
// MODE 0: plain f32 C write (split-K via blockIdx.z).
// MODE 1: in-proj fused epilogue (bias + causal conv + silu -> xcb / sresb).
// ---------------------------------------------------------------------------
template<int MODE>
__global__ __launch_bounds__(256) void gemm_bf16(
    const u16* __restrict__ A, int lda,
    const u16* __restrict__ W, int ldw,
    float* __restrict__ C, int ldc, int N,
    int kIters, int kzStep, int czStep,
    const float* __restrict__ in_b, const float* __restrict__ conv_w,
    const float* __restrict__ conv_b,
    u16* __restrict__ xcb, u16* __restrict__ sresb)
{
    constexpr int SMEM = (MODE == 1) ? (128 * 129 * 4) : 32768;
    __shared__ char smem[SMEM];
    u16* As = (u16*)smem;              // [2][4096] u16
    u16* Ws = (u16*)(smem + 16384);    // [2][4096] u16

    const int tid  = threadIdx.x;
    const int lane = tid & 63;
    const int wv   = tid >> 6;
    const int wr   = wv >> 1, wc = wv & 1;
    const int m0 = blockIdx.x * 128, n0 = blockIdx.y * 128;

    A += (size_t)blockIdx.z * kzStep;
    W += (size_t)blockIdx.z * kzStep;
    C += (size_t)blockIdx.z * czStep;

    const int srow = tid >> 2, scol = (tid & 3) * 8;
    const u16* Ag = A + (size_t)(m0 + srow) * lda + scol;
    int wrow0 = n0 + srow;      if (wrow0 > N - 1) wrow0 = N - 1;
    int wrow1 = n0 + 64 + srow; if (wrow1 > N - 1) wrow1 = N - 1;
    const u16* Wg0 = W + (size_t)wrow0 * ldw + scol;
    const u16* Wg1 = W + (size_t)wrow1 * ldw + scol;

    const int frow = lane & 15;
    const int fk   = (lane >> 4) * 8;

    f32x4 acc[4][4] = {};

    ASYNC_CP(Ag, As + wv * 512);
    ASYNC_CP(Ag + (size_t)64 * lda, As + 2048 + wv * 512);
    ASYNC_CP(Wg0, Ws + wv * 512);
    ASYNC_CP(Wg1, Ws + 2048 + wv * 512);
    __syncthreads();

    for (int kt = 0; kt < kIters; ++kt) {
        const int cur = (kt & 1) * 4096;
        const int nxt = 4096 - cur;
        if (kt + 1 < kIters) {
            const int ko = (kt + 1) * 32;
            ASYNC_CP(Ag + ko, As + nxt + wv * 512);
            ASYNC_CP(Ag + ko + (size_t)64 * lda, As + nxt + 2048 + wv * 512);
            ASYNC_CP(Wg0 + ko, Ws + nxt + wv * 512);
            ASYNC_CP(Wg1 + ko, Ws + nxt + 2048 + wv * 512);
        }
        bf16x8 af[4], bf[4];
#pragma unroll
        for (int m = 0; m < 4; ++m)
            af[m] = *(const bf16x8*)&As[cur + (wr * 64 + m * 16 + frow) * 32 + fk];
#pragma unroll
        for (int n = 0; n < 4; ++n)
            bf[n] = *(const bf16x8*)&Ws[cur + (wc * 64 + n * 16 + frow) * 32 + fk];
#pragma unroll
        for (int m = 0; m < 4; ++m)
#pragma unroll
            for (int n = 0; n < 4; ++n)
                acc[m][n] = MFMA16(af[m], bf[n], acc[m][n]);
        __syncthreads();
    }

    if (MODE == 0) {
#pragma unroll
        for (int n = 0; n < 4; ++n) {
            int col = n0 + wc * 64 + n * 16 + (lane & 15);
            if (col < N) {
#pragma unroll
                for (int m = 0; m < 4; ++m) {
                    int rbase = m0 + wr * 64 + m * 16 + (lane >> 4) * 4;
#pragma unroll
                    for (int j = 0; j < 4; ++j)
                        C[(size_t)(rbase + j) * ldc + col] = acc[m][n][j];
                }
            }
        }
    } else {
        float* tile = (float*)smem;
#pragma unroll
        for (int m = 0; m < 4; ++m) {
            int r = wr * 64 + m * 16 + (lane >> 4) * 4;
#pragma unroll
            for (int n = 0; n < 4; ++n) {
                int c = wc * 64 + n * 16 + (lane & 15);
#pragma unroll
                for (int j = 0; j < 4; ++j)
                    tile[(r + j) * 129 + c] = acc[m][n][j];
            }
        }
        __syncthreads();

        const bool isXs = (blockIdx.y < 8);
        const int cA = (tid * 2) & 127;
        const int rb = tid >> 6;
        const float ib0 = in_b[n0 + cA];
        const float ib1 = in_b[n0 + cA + 1];
        if (isXs) {
            const int e0 = n0 + cA;
            float4 w0 = *(const float4*)&conv_w[e0 * DC_];
            float4 w1 = *(const float4*)&conv_w[(e0 + 1) * DC_];
            float cb0 = conv_b[e0], cb1 = conv_b[e0 + 1];
            for (int it = 0; it < 32; ++it) {
                int r = it * 4 + rb;
                int l = r & 15;
                float c3a = tile[r * 129 + cA] + ib0;
                float c3b = tile[r * 129 + cA + 1] + ib1;
                float c2a = (l >= 1) ? tile[(r - 1) * 129 + cA] + ib0 : 0.f;
                float c2b = (l >= 1) ? tile[(r - 1) * 129 + cA + 1] + ib1 : 0.f;
                float c1a = (l >= 2) ? tile[(r - 2) * 129 + cA] + ib0 : 0.f;
                float c1b = (l >= 2) ? tile[(r - 2) * 129 + cA + 1] + ib1 : 0.f;
                float c0a = (l >= 3) ? tile[(r - 3) * 129 + cA] + ib0 : 0.f;
                float c0b = (l >= 3) ? tile[(r - 3) * 129 + cA + 1] + ib1 : 0.f;
                float va = cb0 + w0.x * c0a + w0.y * c1a + w0.z * c2a + w0.w * c3a;
                float vb = cb1 + w1.x * c0b + w1.y * c1b + w1.z * c2b + w1.w * c3b;
                u16x2 o; o[0] = f2bf(silu_f(va)); o[1] = f2bf(silu_f(vb));
                *(u16x2*)&xcb[(size_t)(m0 + r) * DI_ + e0] = o;
            }
        } else {
            const int e0 = n0 - 1024 + cA;
            for (int it = 0; it < 32; ++it) {
                int r = it * 4 + rb;
                float va = silu_f(tile[r * 129 + cA] + ib0);
                float vb = silu_f(tile[r * 129 + cA + 1] + ib1);
                u16x2 o; o[0] = f2bf(va); o[1] = f2bf(vb);
                *(u16x2*)&sresb[(size_t)(m0 + r) * DI_ + e0] = o;
            }
        }
    }
}

// ---------------------------------------------------------------------------
// MEGASCAN: per (b,c) block (256 blocks, 1024 threads = 16 waves):
//   x-proj MFMA -> dt-proj MFMA+softplus -> 16-step scan (barrier-free) ->
//   out-proj MFMA -> residual + joint LayerNorm, all fused.
// LDS: xcy[16][1032]u16 | dtL[16][1024]f32 (alias pxp[4][16][64]) |
//      dbcL[16][64]f32 | dtiL[16][32]bf16 | red[17]f32
// ---------------------------------------------------------------------------
#define XST 1032
__global__ __launch_bounds__(1024, 1) void megascan(
    const u16* __restrict__ xcb, const u16* __restrict__ sresb,
    float* __restrict__ h, u16* __restrict__ hb,
    const u16* __restrict__ xp_wb, const u16* __restrict__ dt_wb,
    const float* __restrict__ dt_b, const float* __restrict__ A_log,
    const float* __restrict__ Dp, const u16* __restrict__ out_wb,
    const float* __restrict__ out_b, const float* __restrict__ ln_w,
    const float* __restrict__ ln_b)
{
    __shared__ __align__(16) char smem[103808];
    u16*   xcy  = (u16*)smem;                    // [16][1032]
    float* dtL  = (float*)(smem + 33024);        // [16][1024]
    float* pxp  = (float*)(smem + 33024);        // [4][16][64] (alias)
    float* dbcL = (float*)(smem + 98560);        // [16][64]
    u16*   dtiL = (u16*)(smem + 102656);         // [16][32]
    float* red  = (float*)(smem + 103680);       // [17]

    const int tid  = threadIdx.x;
    const int lane = tid & 63;
    const int wv   = tid >> 6;
    const int bc   = blockIdx.x;
    const size_t rbase = (size_t)bc * L_;        // row base in [4096,*]

    const int frow = lane & 15;
    const int fkg  = (lane >> 4) * 8;

    // ---- stage xc tile [16][1024] -> LDS (padded rows)
    {
        int r = tid >> 6, c = (tid & 63) * 16;
        const u16* src = xcb + (rbase + r) * DI_ + c;
        u16x8 v0 = *(const u16x8*)src;
        u16x8 v1 = *(const u16x8*)(src + 8);
        *(u16x8*)&xcy[r * XST + c] = v0;
        *(u16x8*)&xcy[r * XST + c + 8] = v1;
    }
    __syncthreads();

    // ---- x-proj: dbc[16,64] = xc[16,1024] x xproj_w[64,1024]^T; waves 0-3
    if (wv < 4) {
        f32x4 xacc[4] = {};
#pragma unroll
        for (int kf = 0; kf < 8; ++kf) {
            int k = wv * 256 + kf * 32 + fkg;
            bf16x8 a = *(const bf16x8*)&xcy[frow * XST + k];
#pragma unroll
            for (int ef = 0; ef < 4; ++ef) {
                bf16x8 b = *(const bf16x8*)&xp_wb[(size_t)(ef * 16 + frow) * DI_ + k];
                xacc[ef] = MFMA16(a, b, xacc[ef]);
            }
        }
#pragma unroll
        for (int ef = 0; ef < 4; ++ef)
#pragma unroll
            for (int j = 0; j < 4; ++j)
                pxp[(wv * 16 + (lane >> 4) * 4 + j) * 64 + ef * 16 + frow] = xacc[ef][j];
    }
    __syncthreads();

    // ---- reduce 4 partials -> dbcL f32 + dtiL bf16
    {
        int l = tid >> 6, e = tid & 63;
        float v = pxp[l * 64 + e] + pxp[1024 + l * 64 + e]
                + pxp[2048 + l * 64 + e] + pxp[3072 + l * 64 + e];
        dbcL[l * 64 + e] = v;
        if (e < DT_) dtiL[l * DT_ + e] = f2bf(v);
    }
    __syncthreads();

    // ---- dt-proj: dt[16,1024] = dt_in[16,32] x dt_w[1024,32]^T, +dt_b, softplus
    {
        bf16x8 a = *(const bf16x8*)&dtiL[frow * DT_ + fkg];
#pragma unroll
        for (int nf = 0; nf < 4; ++nf) {
            int d = wv * 64 + nf * 16 + frow;
            bf16x8 b = *(const bf16x8*)&dt_wb[(size_t)d * DT_ + fkg];
            f32x4 c = {};
            c = MFMA16(a, b, c);
            float dtb = dt_b[d];
#pragma unroll
            for (int j = 0; j < 4; ++j) {
                int l = (lane >> 4) * 4 + j;
                float din = c[j] + dtb;
                float dtv = (din > 20.f) ? din : __logf(1.f + __expf(din));
                dtL[l * DI_ + d] = dtv;
            }
        }
    }
    __syncthreads();

    // ---- scan (barrier-free): thread d; y overwrites xc in LDS
    {
        const int d = tid;
        float Arow[DS_];
#pragma unroll
        for (int s = 0; s < DS_; ++s) Arow[s] = -__expf(A_log[d * DS_ + s]);
        float Dpd = Dp[d];
        float st[DS_];
#pragma unroll
        for (int s = 0; s < DS_; ++s) st[s] = 0.f;
        const u16* srp = sresb + rbase * DI_ + d;
        for (int l = 0; l < L_; ++l) {
            float dtv = dtL[l * DI_ + d];
            float u = bf2f(xcy[l * XST + d]);
            float du = dtv * u;
            float y = 0.f;
#pragma unroll
            for (int s = 0; s < DS_; ++s) {
                float dA = __expf(dtv * Arow[s]);
                st[s] = dA * st[s] + du * dbcL[l * 64 + DT_ + s];
                y += st[s] * dbcL[l * 64 + DT_ + DS_ + s];
            }
            float sres = bf2f(srp[(size_t)l * DI_]);
            xcy[l * XST + d] = f2bf((y + Dpd * u) * sres);
        }
    }
    __syncthreads();

    // ---- out-proj: upd[16,512] = y[16,1024] x out_w[512,1024]^T
    // wave wv owns cols wv*32 .. wv*32+31 (2 nfrags), accumulates full K.
    f32x4 oacc[2] = {};
    for (int kf = 0; kf < 32; ++kf) {
        int k = kf * 32 + fkg;
        bf16x8 a = *(const bf16x8*)&xcy[frow * XST + k];
#pragma unroll
        for (int nf = 0; nf < 2; ++nf) {
            bf16x8 b = *(const bf16x8*)&out_wb[(size_t)(wv * 32 + nf * 16 + frow) * DI_ + k];
            oacc[nf] = MFMA16(a, b, oacc[nf]);
        }
    }

    // ---- residual + joint LayerNorm from registers
    float v[8];
    float s = 0.f;
#pragma unroll
    for (int nf = 0; nf < 2; ++nf) {
        int d = wv * 32 + nf * 16 + frow;
        float ob = out_b[d];
#pragma unroll
        for (int j = 0; j < 4; ++j) {
            int l = (lane >> 4) * 4 + j;
            float val = h[(rbase + l) * D_ + d] + oacc[nf][j] + ob;
            v[nf * 4 + j] = val;
            s += val;
        }
    }
#pragma unroll
    for (int o = 32; o > 0; o >>= 1) s += __shfl_down(s, o);
    if (lane == 0) red[wv] = s;
    __syncthreads();
    if (tid == 0) {
        float t = 0.f;
#pragma unroll
        for (int w2 = 0; w2 < 16; ++w2) t += red[w2];
        red[16] = t * (1.f / 8192.f);
    }
    __syncthreads();
    const float mu = red[16];
    __syncthreads();

    float s2 = 0.f;
#pragma unroll
    for (int i = 0; i < 8; ++i) { float dv = v[i] - mu; s2 += dv * dv; }
#pragma unroll
    for (int o = 32; o > 0; o >>= 1) s2 += __shfl_down(s2, o);
    if (lane == 0) red[wv] = s2;
    __syncthreads();
    if (tid == 0) {
        float t = 0.f;
#pragma unroll
        for (int w2 = 0; w2 < 16; ++w2) t += red[w2];
        red[16] = rsqrtf(t * (1.f / 8192.f) + EPS_);
    }
    __syncthreads();
    const float rstd = red[16];

#pragma unroll
    for (int nf = 0; nf < 2; ++nf) {
        int d = wv * 32 + nf * 16 + frow;
#pragma unroll
        for (int j = 0; j < 4; ++j) {
            int l = (lane >> 4) * 4 + j;
            int idx = l * D_ + d;
            float o = (v[nf * 4 + j] - mu) * rstd * ln_w[idx] + ln_b[idx];
            h[(rbase + l) * D_ + d] = o;
            hb[(rbase + l) * D_ + d] = f2bf(o);
        }
    }
}

// out[b,s,c] = step_b[s] + sum_ks part[ks, b*CN+c, s]   (32 slices)
__global__ __launch_bounds__(256) void head_reduce_kernel(
    const float* __restrict__ part, const float* __restrict__ step_b,
    float* __restrict__ out)
{
    int j = blockIdx.x * 256 + threadIdx.x;  // (b*S+s)*CN + c
    int c = j & (CN_ - 1);
    int bs = j >> 7;
    int s = bs & (S_ - 1);
    int b = bs >> 8;
    int m = b * CN_ + c;
    float acc = step_b[s];
#pragma unroll
    for (int ks = 0; ks < 32; ++ks) acc += part[((size_t)ks * 256 + m) * 256 + s];
    out[j] = acc;
}

// ---------------------------------------------------------------------------
extern "C" void kernel_launch(void* const* d_in, const int* in_sizes, int n_in,
                              void* d_out, int out_size, void* d_ws, size_t ws_size,
                              hipStream_t stream)
{
    const float* x      = (const float*)d_in[0];
    const float* emb_w  = (const float*)d_in[1];
    const float* emb_b  = (const float*)d_in[2];
    const float* in_w   = (const float*)d_in[3];
    const float* in_b   = (const float*)d_in[4];
    const float* conv_w = (const float*)d_in[5];
    const float* conv_b = (const float*)d_in[6];
    const float* xproj_w= (const float*)d_in[7];
    const float* dt_w   = (const float*)d_in[8];
    const float* dt_b   = (const float*)d_in[9];
    const float* A_log  = (const float*)d_in[10];
    const float* Dp     = (const float*)d_in[11];
    const float* out_w  = (const float*)d_in[12];
    const float* out_b  = (const float*)d_in[13];
    const float* ln_w   = (const float*)d_in[14];
    const float* ln_b   = (const float*)d_in[15];
    const float* step_w = (const float*)d_in[16];
    const float* step_b = (const float*)d_in[17];
    float* out = (float*)d_out;

    char* ws = (char*)d_ws;
    float* h     = (float*)(ws);                    //  8 MiB [4096,512]
    u16*   hb    = (u16*)  (ws + 8388608);          //  4 MiB
    u16*   xcb   = (u16*)  (ws + 12582912);         //  8 MiB [4096,1024]
    u16*   sresb = (u16*)  (ws + 20971520);         //  8 MiB
    u16*   in_wb = (u16*)  (ws + 29360128);         //  8 MiB
    u16*   out_wb= (u16*)  (ws + 37748736);         //  4 MiB
    u16*   xp_wb = (u16*)  (ws + 41943040);         //  0.5 MiB
    u16*   st_wb = (u16*)  (ws + 42467328);         //  4 MiB
    u16*   dt_wb = (u16*)  (ws + 46661632);         //  0.25 MiB
    float* part  = (float*)(ws + 46923776);         //  8 MiB [32,256,256]

    const int M = B_ * CN_ * L_;  // 4096

    cvt_all<<<4288, 256, 0, stream>>>(in_w, out_w, xproj_w, step_w, dt_w,
                                      in_wb, out_wb, xp_wb, st_wb, dt_wb);
    embed_kernel<<<M, 256, 0, stream>>>(x, emb_w, emb_b, h, hb);

    for (int i = 0; i < NB_; ++i) {
        // in-proj + bias + causal conv + silu + res-silu (fused epilogue)
        gemm_bf16<1><<<dim3(M / 128, 16, 1), 256, 0, stream>>>(
            hb, D_, in_wb + (size_t)i * 2 * DI_ * D_, D_,
            nullptr, 0, 2 * DI_, D_ / 32, 0, 0,
            in_b + (size_t)i * 2 * DI_, conv_w + (size_t)i * DI_ * DC_,
            conv_b + (size_t)i * DI_, xcb, sresb);
        // x-proj + dt-proj + scan + out-proj + residual + LN (one launch)
        megascan<<<B_ * CN_, 1024, 0, stream>>>(
            xcb, sresb, h, hb,
            xp_wb + (size_t)i * 64 * DI_, dt_wb + (size_t)i * DI_ * DT_,
            dt_b + (size_t)i * DI_, A_log + (size_t)i * DI_ * DS_,
            Dp + (size_t)i * DI_, out_wb + (size_t)i * D_ * DI_,
            out_b + (size_t)i * D_,
            ln_w + (size_t)i * L_ * D_, ln_b + (size_t)i * L_ * D_);
    }

    // head: split-K 32 MFMA GEMM + reduce/transpose
    gemm_bf16<0><<<dim3(2, 2, 32), 256, 0, stream>>>(
        hb, L_ * D_, st_wb, L_ * D_,
        part, S_, S_, 8, 256, 256 * 256,
        nullptr, nullptr, nullptr, nullptr, nullptr);
    head_reduce_kernel<<<(B_ * S_ * CN_) / 256, 256, 0, stream>>>(part, step_b, out);
}

// Round 5
// 345.803 us; speedup vs baseline: 5.2826x; 1.0834x over previous
//
#include <hip/hip_runtime.h>
#include <math.h>

// dims
#define B_ 2
#define S_ 256
#define CN_ 128
#define P_ 16
#define D_ 512
#define DI_ 1024
#define DS_ 16
#define DC_ 4
#define DT_ 32
#define NB_ 4
#define L_ 16
#define EPS_ 1e-5f

typedef unsigned short u16;
typedef __bf16 bf16x8 __attribute__((ext_vector_type(8)));
typedef float f32x4 __attribute__((ext_vector_type(4)));
typedef u16 u16x8 __attribute__((ext_vector_type(8)));
typedef u16 u16x4 __attribute__((ext_vector_type(4)));
typedef u16 u16x2 __attribute__((ext_vector_type(2)));

__device__ __forceinline__ float silu_f(float x) { return x / (1.f + __expf(-x)); }

__device__ __forceinline__ u16 f2bf(float f) {
    union { float f; unsigned u; } v; v.f = f;
    return (u16)((v.u + 0x7fffu + ((v.u >> 16) & 1u)) >> 16);
}
__device__ __forceinline__ float bf2f(u16 b) {
    union { unsigned u; float f; } v; v.u = ((unsigned)b) << 16; return v.f;
}

#define ASYNC_CP(gsrc, ldst)                                                        \
    __builtin_amdgcn_global_load_lds(                                               \
        (const __attribute__((address_space(1))) void*)(gsrc),                      \
        (__attribute__((address_space(3))) void*)(ldst), 16, 0, 0)

#define MFMA16(a, b, c) __builtin_amdgcn_mfma_f32_16x16x32_bf16((a), (b), (c), 0, 0, 0)

// ---------------------------------------------------------------------------
// Fused f32->bf16 weight convert. Segments: in_w(2048 blk), out_w(1024),
// xproj_w(128), step_w(1024), dt_w(64). 8 elems/thread.
// ---------------------------------------------------------------------------
__global__ __launch_bounds__(256) void cvt_all(
    const float* __restrict__ in_w, const float* __restrict__ out_w,
    const float* __restrict__ xproj_w, const float* __restrict__ step_w,
    const float* __restrict__ dt_w,
    u16* __restrict__ in_wb, u16* __restrict__ out_wb,
    u16* __restrict__ xp_wb, u16* __restrict__ st_wb, u16* __restrict__ dt_wb)
{
    int blk = blockIdx.x;
    const float* src; u16* dst; int base;
    if (blk < 2048)      { src = in_w;    dst = in_wb;  base = blk; }
    else if (blk < 3072) { src = out_w;   dst = out_wb; base = blk - 2048; }
    else if (blk < 3200) { src = xproj_w; dst = xp_wb;  base = blk - 3072; }
    else if (blk < 4224) { src = step_w;  dst = st_wb;  base = blk - 3200; }
    else                 { src = dt_w;    dst = dt_wb;  base = blk - 4224; }
    int i = (base * 256 + threadIdx.x) * 8;
    float4 a = *(const float4*)(src + i);
    float4 b = *(const float4*)(src + i + 4);
    u16x8 o;
    o[0] = f2bf(a.x); o[1] = f2bf(a.y); o[2] = f2bf(a.z); o[3] = f2bf(a.w);
    o[4] = f2bf(b.x); o[5] = f2bf(b.y); o[6] = f2bf(b.z); o[7] = f2bf(b.w);
    *(u16x8*)(dst + i) = o;
}

// ---------------------------------------------------------------------------
// Embed: h[b,c,l,d] = sum_p x[b, l*16+p, c] * emb_w[d,p] + emb_b[d]
// ---------------------------------------------------------------------------
__global__ __launch_bounds__(256) void embed_kernel(
    const float* __restrict__ x, const float* __restrict__ emb_w,
    const float* __restrict__ emb_b, float* __restrict__ h, u16* __restrict__ hb)
{
    int bid = blockIdx.x;          // bc*L + l
    int l   = bid & (L_ - 1);
    int bc  = bid >> 4;
    int b   = bc >> 7;
    int c   = bc & 127;
    __shared__ float xp[P_];
    int tid = threadIdx.x;
    if (tid < P_) xp[tid] = x[(size_t)(b * S_ + l * P_ + tid) * CN_ + c];
    __syncthreads();
    for (int dd = tid; dd < D_; dd += 256) {
        float acc = emb_b[dd];
#pragma unroll
        for (int p = 0; p < P_; ++p) acc += xp[p] * emb_w[dd * P_ + p];
        h[(size_t)bid * D_ + dd] = acc;
        hb[(size_t)bid * D_ + dd] = f2bf(acc);
    }
}

// ---------------------------------------------------------------------------
// bf16 MFMA NT GEMM, 128x128 tile, BK=32, 4 waves, double-buffered LDS.
// MODE 0: plain f32 C write (split-K via blockIdx.z).
// MODE 1: in-proj fused epilogue (bias + causal conv + silu -> xcb / sresb).
// ---------------------------------------------------------------------------
template<int MODE>
__global__ __launch_bounds__(256) void gemm_bf16(
    const u16* __restrict__ A, int lda,
    const u16* __restrict__ W, int ldw,
    float* __restrict__ C, int ldc, int N,
    int kIters, int kzStep, int czStep,
    const float* __restrict__ in_b, const float* __restrict__ conv_w,
    const float* __restrict__ conv_b,
    u16* __restrict__ xcb, u16* __restrict__ sresb)
{
    constexpr int SMEM = (MODE == 1) ? (128 * 129 * 4) : 32768;
    __shared__ char smem[SMEM];
    u16* As = (u16*)smem;              // [2][4096] u16
    u16* Ws = (u16*)(smem + 16384);    // [2][4096] u16

    const int tid  = threadIdx.x;
    const int lane = tid & 63;
    const int wv   = tid >> 6;
    const int wr   = wv >> 1, wc = wv & 1;
    const int m0 = blockIdx.x * 128, n0 = blockIdx.y * 128;

    A += (size_t)blockIdx.z * kzStep;
    W += (size_t)blockIdx.z * kzStep;
    C += (size_t)blockIdx.z * czStep;

    const int srow = tid >> 2, scol = (tid & 3) * 8;
    const u16* Ag = A + (size_t)(m0 + srow) * lda + scol;
    int wrow0 = n0 + srow;      if (wrow0 > N - 1) wrow0 = N - 1;
    int wrow1 = n0 + 64 + srow; if (wrow1 > N - 1) wrow1 = N - 1;
    const u16* Wg0 = W + (size_t)wrow0 * ldw + scol;
    const u16* Wg1 = W + (size_t)wrow1 * ldw + scol;

    const int frow = lane & 15;
    const int fk   = (lane >> 4) * 8;

    f32x4 acc[4][4] = {};

    ASYNC_CP(Ag, As + wv * 512);
    ASYNC_CP(Ag + (size_t)64 * lda, As + 2048 + wv * 512);
    ASYNC_CP(Wg0, Ws + wv * 512);
    ASYNC_CP(Wg1, Ws + 2048 + wv * 512);
    __syncthreads();

    for (int kt = 0; kt < kIters; ++kt) {
        const int cur = (kt & 1) * 4096;
        const int nxt = 4096 - cur;
        if (kt + 1 < kIters) {
            const int ko = (kt + 1) * 32;
            ASYNC_CP(Ag + ko, As + nxt + wv * 512);
            ASYNC_CP(Ag + ko + (size_t)64 * lda, As + nxt + 2048 + wv * 512);
            ASYNC_CP(Wg0 + ko, Ws + nxt + wv * 512);
            ASYNC_CP(Wg1 + ko, Ws + nxt + 2048 + wv * 512);
        }
        bf16x8 af[4], bf[4];
#pragma unroll
        for (int m = 0; m < 4; ++m)
            af[m] = *(const bf16x8*)&As[cur + (wr * 64 + m * 16 + frow) * 32 + fk];
#pragma unroll
        for (int n = 0; n < 4; ++n)
            bf[n] = *(const bf16x8*)&Ws[cur + (wc * 64 + n * 16 + frow) * 32 + fk];
#pragma unroll
        for (int m = 0; m < 4; ++m)
#pragma unroll
            for (int n = 0; n < 4; ++n)
                acc[m][n] = MFMA16(af[m], bf[n], acc[m][n]);
        __syncthreads();
    }

    if (MODE == 0) {
#pragma unroll
        for (int n = 0; n < 4; ++n) {
            int col = n0 + wc * 64 + n * 16 + (lane & 15);
            if (col < N) {
#pragma unroll
                for (int m = 0; m < 4; ++m) {
                    int rbase = m0 + wr * 64 + m * 16 + (lane >> 4) * 4;
#pragma unroll
                    for (int j = 0; j < 4; ++j)
                        C[(size_t)(rbase + j) * ldc + col] = acc[m][n][j];
                }
            }
        }
    } else {
        float* tile = (float*)smem;
#pragma unroll
        for (int m = 0; m < 4; ++m) {
            int r = wr * 64 + m * 16 + (lane >> 4) * 4;
#pragma unroll
            for (int n = 0; n < 4; ++n) {
                int c = wc * 64 + n * 16 + (lane & 15);
#pragma unroll
                for (int j = 0; j < 4; ++j)
                    tile[(r + j) * 129 + c] = acc[m][n][j];
            }
        }
        __syncthreads();

        const bool isXs = (blockIdx.y < 8);
        const int cA = (tid * 2) & 127;
        const int rb = tid >> 6;
        const float ib0 = in_b[n0 + cA];
        const float ib1 = in_b[n0 + cA + 1];
        if (isXs) {
            const int e0 = n0 + cA;
            float4 w0 = *(const float4*)&conv_w[e0 * DC_];
            float4 w1 = *(const float4*)&conv_w[(e0 + 1) * DC_];
            float cb0 = conv_b[e0], cb1 = conv_b[e0 + 1];
            for (int it = 0; it < 32; ++it) {
                int r = it * 4 + rb;
                int l = r & 15;
                float c3a = tile[r * 129 + cA] + ib0;
                float c3b = tile[r * 129 + cA + 1] + ib1;
                float c2a = (l >= 1) ? tile[(r - 1) * 129 + cA] + ib0 : 0.f;
                float c2b = (l >= 1) ? tile[(r - 1) * 129 + cA + 1] + ib1 : 0.f;
                float c1a = (l >= 2) ? tile[(r - 2) * 129 + cA] + ib0 : 0.f;
                float c1b = (l >= 2) ? tile[(r - 2) * 129 + cA + 1] + ib1 : 0.f;
                float c0a = (l >= 3) ? tile[(r - 3) * 129 + cA] + ib0 : 0.f;
                float c0b = (l >= 3) ? tile[(r - 3) * 129 + cA + 1] + ib1 : 0.f;
                float va = cb0 + w0.x * c0a + w0.y * c1a + w0.z * c2a + w0.w * c3a;
                float vb = cb1 + w1.x * c0b + w1.y * c1b + w1.z * c2b + w1.w * c3b;
                u16x2 o; o[0] = f2bf(silu_f(va)); o[1] = f2bf(silu_f(vb));
                *(u16x2*)&xcb[(size_t)(m0 + r) * DI_ + e0] = o;
            }
        } else {
            const int e0 = n0 - 1024 + cA;
            for (int it = 0; it < 32; ++it) {
                int r = it * 4 + rb;
                float va = silu_f(tile[r * 129 + cA] + ib0);
                float vb = silu_f(tile[r * 129 + cA + 1] + ib1);
                u16x2 o; o[0] = f2bf(va); o[1] = f2bf(vb);
                *(u16x2*)&sresb[(size_t)(m0 + r) * DI_ + e0] = o;
            }
        }
    }
}

// ---------------------------------------------------------------------------
// SCANF: per (b,c) block (256 blocks, 1024 threads = 16 waves):
//   x-proj MFMA (16-wave K-split + LDS reduce) -> dt-proj MFMA + softplus ->
//   16-step scan (barrier-free, thread-per-d) -> gate -> yb (bf16, global).
// LDS: xcy[16][1032]u16 | pxp[16][16][64]f32 (alias dtL[16][1024]f32) |
//      dbcL[16][64]f32 | dtiL[16][32]bf16
// ---------------------------------------------------------------------------
#define XST 1032
__global__ __launch_bounds__(1024, 1) void scanf_kernel(
    const u16* __restrict__ xcb, const u16* __restrict__ sresb,
    const u16* __restrict__ xp_wb, const u16* __restrict__ dt_wb,
    const float* __restrict__ dt_b, const float* __restrict__ A_log,
    const float* __restrict__ Dp, u16* __restrict__ yb)
{
    __shared__ __align__(16) char smem[103808];
    u16*   xcy  = (u16*)smem;                    // [16][1032]
    float* pxp  = (float*)(smem + 33024);        // [16][16][64]
    float* dtL  = (float*)(smem + 33024);        // [16][1024] (alias)
    float* dbcL = (float*)(smem + 98560);        // [16][64]
    u16*   dtiL = (u16*)(smem + 102656);         // [16][32]

    const int tid  = threadIdx.x;
    const int lane = tid & 63;
    const int wv   = tid >> 6;
    const int bc   = blockIdx.x;
    const size_t rbase = (size_t)bc * L_;

    const int frow = lane & 15;
    const int fkg  = (lane >> 4) * 8;

    // ---- stage xc tile [16][1024] -> LDS (padded rows)
    {
        int r = tid >> 6, c = (tid & 63) * 16;
        const u16* src = xcb + (rbase + r) * DI_ + c;
        u16x8 v0 = *(const u16x8*)src;
        u16x8 v1 = *(const u16x8*)(src + 8);
        *(u16x8*)&xcy[r * XST + c] = v0;
        *(u16x8*)&xcy[r * XST + c + 8] = v1;
    }
    __syncthreads();

    // ---- x-proj: dbc[16,64] = xc[16,1024] x xproj_w[64,1024]^T
    // wave wv covers K-slice [wv*64, wv*64+64)
    {
        f32x4 xacc[4] = {};
#pragma unroll
        for (int kf = 0; kf < 2; ++kf) {
            int k = wv * 64 + kf * 32 + fkg;
            bf16x8 a = *(const bf16x8*)&xcy[frow * XST + k];
#pragma unroll
            for (int ef = 0; ef < 4; ++ef) {
                bf16x8 b = *(const bf16x8*)&xp_wb[(size_t)(ef * 16 + frow) * DI_ + k];
                xacc[ef] = MFMA16(a, b, xacc[ef]);
            }
        }
#pragma unroll
        for (int ef = 0; ef < 4; ++ef)
#pragma unroll
            for (int j = 0; j < 4; ++j)
                pxp[wv * 1024 + ((lane >> 4) * 4 + j) * 64 + ef * 16 + frow] = xacc[ef][j];
    }
    __syncthreads();

    // ---- reduce 16 partials -> dbcL f32 + dtiL bf16
    {
        int l = tid >> 6, e = tid & 63;
        float v = 0.f;
#pragma unroll
        for (int w = 0; w < 16; ++w) v += pxp[w * 1024 + l * 64 + e];
        dbcL[l * 64 + e] = v;
        if (e < DT_) dtiL[l * DT_ + e] = f2bf(v);
    }
    __syncthreads();

    // ---- dt-proj: dt[16,1024] = dt_in[16,32] x dt_w[1024,32]^T, +dt_b, softplus
    // (dtL overwrites pxp — safe after barrier)
    {
        bf16x8 a = *(const bf16x8*)&dtiL[frow * DT_ + fkg];
#pragma unroll
        for (int nf = 0; nf < 4; ++nf) {
            int d = wv * 64 + nf * 16 + frow;
            bf16x8 b = *(const bf16x8*)&dt_wb[(size_t)d * DT_ + fkg];
            f32x4 c = {};
            c = MFMA16(a, b, c);
            float dtb = dt_b[d];
#pragma unroll
            for (int j = 0; j < 4; ++j) {
                int l = (lane >> 4) * 4 + j;
                float din = c[j] + dtb;
                float dtv = (din > 20.f) ? din : __logf(1.f + __expf(din));
                dtL[l * DI_ + d] = dtv;
            }
        }
    }
    __syncthreads();

    // ---- scan (barrier-free): thread d; gate; write yb coalesced
    {
        const int d = tid;
        float Arow[DS_];
        {
            float4 a0 = *(const float4*)&A_log[d * DS_ + 0];
            float4 a1 = *(const float4*)&A_log[d * DS_ + 4];
            float4 a2 = *(const float4*)&A_log[d * DS_ + 8];
            float4 a3 = *(const float4*)&A_log[d * DS_ + 12];
            Arow[0] = -__expf(a0.x); Arow[1] = -__expf(a0.y);
            Arow[2] = -__expf(a0.z); Arow[3] = -__expf(a0.w);
            Arow[4] = -__expf(a1.x); Arow[5] = -__expf(a1.y);
            Arow[6] = -__expf(a1.z); Arow[7] = -__expf(a1.w);
            Arow[8] = -__expf(a2.x); Arow[9] = -__expf(a2.y);
            Arow[10] = -__expf(a2.z); Arow[11] = -__expf(a2.w);
            Arow[12] = -__expf(a3.x); Arow[13] = -__expf(a3.y);
            Arow[14] = -__expf(a3.z); Arow[15] = -__expf(a3.w);
        }
        float Dpd = Dp[d];
        float st[DS_];
#pragma unroll
        for (int s = 0; s < DS_; ++s) st[s] = 0.f;
        const u16* srp = sresb + rbase * DI_ + d;
        u16* yp = yb + rbase * DI_ + d;
        for (int l = 0; l < L_; ++l) {
            float dtv = dtL[l * DI_ + d];
            float u = bf2f(xcy[l * XST + d]);
            float du = dtv * u;
            float y = 0.f;
#pragma unroll
            for (int s = 0; s < DS_; ++s) {
                float dA = __expf(dtv * Arow[s]);
                st[s] = dA * st[s] + du * dbcL[l * 64 + DT_ + s];
                y += st[s] * dbcL[l * 64 + DT_ + DS_ + s];
            }
            float sres = bf2f(srp[(size_t)l * DI_]);
            yp[(size_t)l * DI_] = f2bf((y + Dpd * u) * sres);
        }
    }
}

// ---------------------------------------------------------------------------
// Residual add (h + upd0 + upd1 + out_b) + joint LayerNorm over (L,D)=8192.
// float4 throughout. One block per (b,c), 256 threads.
// ---------------------------------------------------------------------------
__global__ __launch_bounds__(256) void ln_kernel(
    float* __restrict__ h, const float* __restrict__ upd,
    const float* __restrict__ out_b,
    const float* __restrict__ ln_w, const float* __restrict__ ln_b,
    u16* __restrict__ hb)
{
    int bc = blockIdx.x;
    int tid = threadIdx.x;
    __shared__ float vbuf[L_ * D_];   // 32 KiB
    __shared__ float ps[4];
    __shared__ float mu_s, rstd_s;

    float4* vb4 = (float4*)vbuf;
    const float4* h4 = (const float4*)(h + (size_t)bc * 8192);
    const float4* u0 = (const float4*)(upd + (size_t)bc * 8192);
    const float4* u1 = (const float4*)(upd + (size_t)2097152 + (size_t)bc * 8192);
    const float4* ob = (const float4*)out_b;

    float s = 0.f;
    for (int j = tid; j < 2048; j += 256) {
        float4 v = h4[j], a = u0[j], b = u1[j], o = ob[j & 127];
        v.x += a.x + b.x + o.x; v.y += a.y + b.y + o.y;
        v.z += a.z + b.z + o.z; v.w += a.w + b.w + o.w;
        vb4[j] = v;
        s += v.x + v.y + v.z + v.w;
    }
#pragma unroll
    for (int o = 32; o > 0; o >>= 1) s += __shfl_down(s, o);
    if ((tid & 63) == 0) ps[tid >> 6] = s;
    __syncthreads();
    if (tid == 0) mu_s = (ps[0] + ps[1] + ps[2] + ps[3]) * (1.f / 8192.f);
    __syncthreads();
    float mu = mu_s;

    float s2 = 0.f;
    for (int j = tid; j < 8192; j += 256) {
        float v = vbuf[j] - mu;
        s2 += v * v;
    }
#pragma unroll
    for (int o = 32; o > 0; o >>= 1) s2 += __shfl_down(s2, o);
    if ((tid & 63) == 0) ps[tid >> 6] = s2;
    __syncthreads();
    if (tid == 0) rstd_s = rsqrtf((ps[0] + ps[1] + ps[2] + ps[3]) * (1.f / 8192.f) + EPS_);
    __syncthreads();
    float rstd = rstd_s;

    const float4* lw4 = (const float4*)ln_w;
    const float4* lb4 = (const float4*)ln_b;
    float4* ho4 = (float4*)(h + (size_t)bc * 8192);
    for (int j = tid; j < 2048; j += 256) {
        float4 v = vb4[j], w = lw4[j], b = lb4[j];
        v.x = (v.x - mu) * rstd * w.x + b.x;
        v.y = (v.y - mu) * rstd * w.y + b.y;
        v.z = (v.z - mu) * rstd * w.z + b.z;
        v.w = (v.w - mu) * rstd * w.w + b.w;
        ho4[j] = v;
        u16x4 ob16; ob16[0] = f2bf(v.x); ob16[1] = f2bf(v.y);
        ob16[2] = f2bf(v.z); ob16[3] = f2bf(v.w);
        *(u16x4*)&hb[(size_t)bc * 8192 + j * 4] = ob16;
    }
}

// out[b,s,c] = step_b[s] + sum_ks part[ks, b*CN+c, s]   (32 slices)
__global__ __launch_bounds__(256) void head_reduce_kernel(
    const float* __restrict__ part, const float* __restrict__ step_b,
    float* __restrict__ out)
{
    int j = blockIdx.x * 256 + threadIdx.x;  // (b*S+s)*CN + c
    int c = j & (CN_ - 1);
    int bs = j >> 7;
    int s = bs & (S_ - 1);
    int b = bs >> 8;
    int m = b * CN_ + c;
    float acc = step_b[s];
#pragma unroll
    for (int ks = 0; ks < 32; ++ks) acc += part[((size_t)ks * 256 + m) * 256 + s];
    out[j] = acc;
}

// ---------------------------------------------------------------------------
extern "C" void kernel_launch(void* const* d_in, const int* in_sizes, int n_in,
                              void* d_out, int out_size, void* d_ws, size_t ws_size,
                              hipStream_t stream)
{
    const float* x      = (const float*)d_in[0];
    const float* emb_w  = (const float*)d_in[1];
    const float* emb_b  = (const float*)d_in[2];
    const float* in_w   = (const float*)d_in[3];
    const float* in_b   = (const float*)d_in[4];
    const float* conv_w = (const float*)d_in[5];
    const float* conv_b = (const float*)d_in[6];
    const float* xproj_w= (const float*)d_in[7];
    const float* dt_w   = (const float*)d_in[8];
    const float* dt_b   = (const float*)d_in[9];
    const float* A_log  = (const float*)d_in[10];
    const float* Dp     = (const float*)d_in[11];
    const float* out_w  = (const float*)d_in[12];
    const float* out_b  = (const float*)d_in[13];
    const float* ln_w   = (const float*)d_in[14];
    const float* ln_b   = (const float*)d_in[15];
    const float* step_w = (const float*)d_in[16];
    const float* step_b = (const float*)d_in[17];
    float* out = (float*)d_out;

    char* ws = (char*)d_ws;
    float* h     = (float*)(ws);                    //  8 MiB [4096,512]
    u16*   hb    = (u16*)  (ws + 8388608);          //  4 MiB
    u16*   xcb   = (u16*)  (ws + 12582912);         //  8 MiB [4096,1024]
    u16*   sresb = (u16*)  (ws + 20971520);         //  8 MiB
    u16*   yb    = (u16*)  (ws + 29360128);         //  8 MiB
    float* upd   = (float*)(ws + 37748736);         // 16 MiB [2][4096][512]
    u16*   in_wb = (u16*)  (ws + 54525952);         //  8 MiB
    u16*   out_wb= (u16*)  (ws + 62914560);         //  4 MiB
    u16*   xp_wb = (u16*)  (ws + 67108864);         //  0.5 MiB
    u16*   st_wb = (u16*)  (ws + 67633152);         //  4 MiB
    u16*   dt_wb = (u16*)  (ws + 71827456);         //  0.25 MiB
    float* part  = (float*)(ws + 72089600);         //  8 MiB [32,256,256]

    const int M = B_ * CN_ * L_;  // 4096

    cvt_all<<<4288, 256, 0, stream>>>(in_w, out_w, xproj_w, step_w, dt_w,
                                      in_wb, out_wb, xp_wb, st_wb, dt_wb);
    embed_kernel<<<M, 256, 0, stream>>>(x, emb_w, emb_b, h, hb);

    for (int i = 0; i < NB_; ++i) {
        // in-proj + bias + causal conv + silu + res-silu (fused epilogue)
        gemm_bf16<1><<<dim3(M / 128, 16, 1), 256, 0, stream>>>(
            hb, D_, in_wb + (size_t)i * 2 * DI_ * D_, D_,
            nullptr, 0, 2 * DI_, D_ / 32, 0, 0,
            in_b + (size_t)i * 2 * DI_, conv_w + (size_t)i * DI_ * DC_,
            conv_b + (size_t)i * DI_, xcb, sresb);
        // x-proj + dt-proj + scan + gate (one launch) -> yb
        scanf_kernel<<<B_ * CN_, 1024, 0, stream>>>(
            xcb, sresb,
            xp_wb + (size_t)i * 64 * DI_, dt_wb + (size_t)i * DI_ * DT_,
            dt_b + (size_t)i * DI_, A_log + (size_t)i * DI_ * DS_,
            Dp + (size_t)i * DI_, yb);
        // out-proj split-K x2 -> upd partials
        gemm_bf16<0><<<dim3(M / 128, 4, 2), 256, 0, stream>>>(
            yb, DI_, out_wb + (size_t)i * D_ * DI_, DI_,
            upd, D_, D_, 16, 512, M * D_,
            nullptr, nullptr, nullptr, nullptr, nullptr);
        // residual (+out_b) + LayerNorm
        ln_kernel<<<B_ * CN_, 256, 0, stream>>>(
            h, upd, out_b + (size_t)i * D_,
            ln_w + (size_t)i * L_ * D_, ln_b + (size_t)i * L_ * D_, hb);
    }

    // head: split-K 32 MFMA GEMM + reduce/transpose
    gemm_bf16<0><<<dim3(2, 2, 32), 256, 0, stream>>>(
        hb, L_ * D_, st_wb, L_ * D_,
        part, S_, S_, 8, 256, 256 * 256,
        nullptr, nullptr, nullptr, nullptr, nullptr);
    head_reduce_kernel<<<(B_ * S_ * CN_) / 256, 256, 0, stream>>>(part, step_b, out);
}

// Round 6
// 340.393 us; speedup vs baseline: 5.3666x; 1.0159x over previous
//
#include <hip/hip_runtime.h>
#include <math.h>

// dims
#define B_ 2
#define S_ 256
#define CN_ 128
#define P_ 16
#define D_ 512
#define DI_ 1024
#define DS_ 16
#define DC_ 4
#define DT_ 32
#define NB_ 4
#define L_ 16
#define EPS_ 1e-5f

typedef unsigned short u16;
typedef __bf16 bf16x8 __attribute__((ext_vector_type(8)));
typedef float f32x4 __attribute__((ext_vector_type(4)));
typedef u16 u16x8 __attribute__((ext_vector_type(8)));
typedef u16 u16x4 __attribute__((ext_vector_type(4)));
typedef u16 u16x2 __attribute__((ext_vector_type(2)));

__device__ __forceinline__ float silu_f(float x) { return x / (1.f + __expf(-x)); }

__device__ __forceinline__ u16 f2bf(float f) {
    union { float f; unsigned u; } v; v.f = f;
    return (u16)((v.u + 0x7fffu + ((v.u >> 16) & 1u)) >> 16);
}
__device__ __forceinline__ float bf2f(u16 b) {
    union { unsigned u; float f; } v; v.u = ((unsigned)b) << 16; return v.f;
}

#define ASYNC_CP(gsrc, ldst)                                                        \
    __builtin_amdgcn_global_load_lds(                                               \
        (const __attribute__((address_space(1))) void*)(gsrc),                      \
        (__attribute__((address_space(3))) void*)(ldst), 16, 0, 0)

#define MFMA16(a, b, c) __builtin_amdgcn_mfma_f32_16x16x32_bf16((a), (b), (c), 0, 0, 0)

// ---------------------------------------------------------------------------
// Fused f32->bf16 weight convert.
// ---------------------------------------------------------------------------
__global__ __launch_bounds__(256) void cvt_all(
    const float* __restrict__ in_w, const float* __restrict__ out_w,
    const float* __restrict__ xproj_w, const float* __restrict__ step_w,
    const float* __restrict__ dt_w,
    u16* __restrict__ in_wb, u16* __restrict__ out_wb,
    u16* __restrict__ xp_wb, u16* __restrict__ st_wb, u16* __restrict__ dt_wb)
{
    int blk = blockIdx.x;
    const float* src; u16* dst; int base;
    if (blk < 2048)      { src = in_w;    dst = in_wb;  base = blk; }
    else if (blk < 3072) { src = out_w;   dst = out_wb; base = blk - 2048; }
    else if (blk < 3200) { src = xproj_w; dst = xp_wb;  base = blk - 3072; }
    else if (blk < 4224) { src = step_w;  dst = st_wb;  base = blk - 3200; }
    else                 { src = dt_w;    dst = dt_wb;  base = blk - 4224; }
    int i = (base * 256 + threadIdx.x) * 8;
    float4 a = *(const float4*)(src + i);
    float4 b = *(const float4*)(src + i + 4);
    u16x8 o;
    o[0] = f2bf(a.x); o[1] = f2bf(a.y); o[2] = f2bf(a.z); o[3] = f2bf(a.w);
    o[4] = f2bf(b.x); o[5] = f2bf(b.y); o[6] = f2bf(b.z); o[7] = f2bf(b.w);
    *(u16x8*)(dst + i) = o;
}

// ---------------------------------------------------------------------------
// Embed
// ---------------------------------------------------------------------------
__global__ __launch_bounds__(256) void embed_kernel(
    const float* __restrict__ x, const float* __restrict__ emb_w,
    const float* __restrict__ emb_b, float* __restrict__ h, u16* __restrict__ hb)
{
    int bid = blockIdx.x;          // bc*L + l
    int l   = bid & (L_ - 1);
    int bc  = bid >> 4;
    int b   = bc >> 7;
    int c   = bc & 127;
    __shared__ float xp[P_];
    int tid = threadIdx.x;
    if (tid < P_) xp[tid] = x[(size_t)(b * S_ + l * P_ + tid) * CN_ + c];
    __syncthreads();
    for (int dd = tid; dd < D_; dd += 256) {
        float acc = emb_b[dd];
#pragma unroll
        for (int p = 0; p < P_; ++p) acc += xp[p] * emb_w[dd * P_ + p];
        h[(size_t)bid * D_ + dd] = acc;
        hb[(size_t)bid * D_ + dd] = f2bf(acc);
    }
}

// ---------------------------------------------------------------------------
// bf16 MFMA NT GEMM, 128x128 tile, BK=32, 4 waves.
// 3-buffer LDS pipeline with counted vmcnt(4) (loads stay in flight across
// the barrier — AITER/T4 pattern). One barrier per K-step.
// MODE 0: f32 C store (split-K via blockIdx.z).
// MODE 1: in-proj fused epilogue (bias + causal conv + silu -> xcb/sresb).
// MODE 2: bf16 C store (split-K partials as u16).
// ---------------------------------------------------------------------------
template<int MODE>
__global__ __launch_bounds__(256) void gemm_bf16(
    const u16* __restrict__ A, int lda,
    const u16* __restrict__ W, int ldw,
    float* __restrict__ C, int ldc, int N,
    int kIters, int kzStep, int czStep,
    const float* __restrict__ in_b, const float* __restrict__ conv_w,
    const float* __restrict__ conv_b,
    u16* __restrict__ xcb, u16* __restrict__ sresb)
{
    // 3 buffers x (As 8KB + Ws 8KB) = 48KB; MODE1 epilogue tile 66KB.
    constexpr int SMEM = (MODE == 1) ? (128 * 129 * 4) : 49152;
    __shared__ __align__(16) char smem[SMEM];

    const int tid  = threadIdx.x;
    const int lane = tid & 63;
    const int wv   = tid >> 6;
    const int wr   = wv >> 1, wc = wv & 1;
    const int m0 = blockIdx.x * 128, n0 = blockIdx.y * 128;

    A += (size_t)blockIdx.z * kzStep;
    W += (size_t)blockIdx.z * kzStep;
    if (MODE == 2) C = (float*)((u16*)C + (size_t)blockIdx.z * czStep);
    else           C += (size_t)blockIdx.z * czStep;

    const int srow = tid >> 2, scol = (tid & 3) * 8;
    const u16* Ag = A + (size_t)(m0 + srow) * lda + scol;
    int wrow0 = n0 + srow;      if (wrow0 > N - 1) wrow0 = N - 1;
    int wrow1 = n0 + 64 + srow; if (wrow1 > N - 1) wrow1 = N - 1;
    const u16* Wg0 = W + (size_t)wrow0 * ldw + scol;
    const u16* Wg1 = W + (size_t)wrow1 * ldw + scol;

    const int frow = lane & 15;
    const int fk   = (lane >> 4) * 8;

    f32x4 acc[4][4] = {};

#define STAGE(buf, kt_)                                                       \
    {                                                                         \
        u16* Asb = (u16*)(smem + (buf) * 16384);                              \
        u16* Wsb = Asb + 4096;                                                \
        const int ko = (kt_) * 32;                                            \
        ASYNC_CP(Ag + ko, Asb + wv * 512);                                    \
        ASYNC_CP(Ag + ko + (size_t)64 * lda, Asb + 2048 + wv * 512);          \
        ASYNC_CP(Wg0 + ko, Wsb + wv * 512);                                   \
        ASYNC_CP(Wg1 + ko, Wsb + 2048 + wv * 512);                            \
    }

    // prologue: stage K-steps 0 and 1
    STAGE(0, 0);
    if (kIters > 1) {
        STAGE(1, 1);
        asm volatile("s_waitcnt vmcnt(4)" ::: "memory");
    } else {
        asm volatile("s_waitcnt vmcnt(0)" ::: "memory");
    }
    __builtin_amdgcn_s_barrier();
    __builtin_amdgcn_sched_barrier(0);

    int cb = 0, sb = 2;
    for (int kt = 0; kt < kIters; ++kt) {
        if (kt + 2 < kIters) STAGE(sb, kt + 2);

        const u16* Asb = (const u16*)(smem + cb * 16384);
        const u16* Wsb = Asb + 4096;
        bf16x8 af[4], bf[4];
#pragma unroll
        for (int m = 0; m < 4; ++m)
            af[m] = *(const bf16x8*)&Asb[(wr * 64 + m * 16 + frow) * 32 + fk];
#pragma unroll
        for (int n = 0; n < 4; ++n)
            bf[n] = *(const bf16x8*)&Wsb[(wc * 64 + n * 16 + frow) * 32 + fk];
#pragma unroll
        for (int m = 0; m < 4; ++m)
#pragma unroll
            for (int n = 0; n < 4; ++n)
                acc[m][n] = MFMA16(af[m], bf[n], acc[m][n]);

        if (kt + 1 < kIters) {
            if (kt + 2 < kIters) asm volatile("s_waitcnt vmcnt(4)" ::: "memory");
            else                 asm volatile("s_waitcnt vmcnt(0)" ::: "memory");
            __builtin_amdgcn_s_barrier();
            __builtin_amdgcn_sched_barrier(0);
        }
        cb = (cb == 2) ? 0 : cb + 1;
        sb = (sb == 2) ? 0 : sb + 1;
    }
#undef STAGE

    if (MODE == 0 || MODE == 2) {
#pragma unroll
        for (int n = 0; n < 4; ++n) {
            int col = n0 + wc * 64 + n * 16 + (lane & 15);
            if (col < N) {
#pragma unroll
                for (int m = 0; m < 4; ++m) {
                    int rbase = m0 + wr * 64 + m * 16 + (lane >> 4) * 4;
#pragma unroll
                    for (int j = 0; j < 4; ++j) {
                        if (MODE == 0)
                            C[(size_t)(rbase + j) * ldc + col] = acc[m][n][j];
                        else
                            ((u16*)C)[(size_t)(rbase + j) * ldc + col] = f2bf(acc[m][n][j]);
                    }
                }
            }
        }
    } else {
        __syncthreads();   // drain + protect smem reuse
        float* tile = (float*)smem;
#pragma unroll
        for (int m = 0; m < 4; ++m) {
            int r = wr * 64 + m * 16 + (lane >> 4) * 4;
#pragma unroll
            for (int n = 0; n < 4; ++n) {
                int c = wc * 64 + n * 16 + (lane & 15);
#pragma unroll
                for (int j = 0; j < 4; ++j)
                    tile[(r + j) * 129 + c] = acc[m][n][j];
            }
        }
        __syncthreads();

        const bool isXs = (blockIdx.y < 8);
        const int cA = (tid * 2) & 127;
        const int rb = tid >> 6;
        const float ib0 = in_b[n0 + cA];
        const float ib1 = in_b[n0 + cA + 1];
        if (isXs) {
            const int e0 = n0 + cA;
            float4 w0 = *(const float4*)&conv_w[e0 * DC_];
            float4 w1 = *(const float4*)&conv_w[(e0 + 1) * DC_];
            float cb0 = conv_b[e0], cb1 = conv_b[e0 + 1];
            for (int it = 0; it < 32; ++it) {
                int r = it * 4 + rb;
                int l = r & 15;
                float c3a = tile[r * 129 + cA] + ib0;
                float c3b = tile[r * 129 + cA + 1] + ib1;
                float c2a = (l >= 1) ? tile[(r - 1) * 129 + cA] + ib0 : 0.f;
                float c2b = (l >= 1) ? tile[(r - 1) * 129 + cA + 1] + ib1 : 0.f;
                float c1a = (l >= 2) ? tile[(r - 2) * 129 + cA] + ib0 : 0.f;
                float c1b = (l >= 2) ? tile[(r - 2) * 129 + cA + 1] + ib1 : 0.f;
                float c0a = (l >= 3) ? tile[(r - 3) * 129 + cA] + ib0 : 0.f;
                float c0b = (l >= 3) ? tile[(r - 3) * 129 + cA + 1] + ib1 : 0.f;
                float va = cb0 + w0.x * c0a + w0.y * c1a + w0.z * c2a + w0.w * c3a;
                float vb = cb1 + w1.x * c0b + w1.y * c1b + w1.z * c2b + w1.w * c3b;
                u16x2 o; o[0] = f2bf(silu_f(va)); o[1] = f2bf(silu_f(vb));
                *(u16x2*)&xcb[(size_t)(m0 + r) * DI_ + e0] = o;
            }
        } else {
            const int e0 = n0 - 1024 + cA;
            for (int it = 0; it < 32; ++it) {
                int r = it * 4 + rb;
                float va = silu_f(tile[r * 129 + cA] + ib0);
                float vb = silu_f(tile[r * 129 + cA + 1] + ib1);
                u16x2 o; o[0] = f2bf(va); o[1] = f2bf(vb);
                *(u16x2*)&sresb[(size_t)(m0 + r) * DI_ + e0] = o;
            }
        }
    }
}

// ---------------------------------------------------------------------------
// SCANF: grid 512 = (b,c) x 2 halves; 512 threads (8 waves).
// Per block: stage xc[16,1024] -> x-proj MFMA (8-wave: 4 ef x 2 K-slices,
// LDS reduce) -> dt-proj MFMA (own 512-d half) + softplus -> 16-step scan
// (thread-per-d, barrier-free) -> gate -> yb bf16.
// LDS ~54.5KB -> 2 blocks/CU.
// ---------------------------------------------------------------------------
#define XST 1032
__global__ __launch_bounds__(512, 4) void scanf_kernel(
    const u16* __restrict__ xcb, const u16* __restrict__ sresb,
    const u16* __restrict__ xp_wb, const u16* __restrict__ dt_wb,
    const float* __restrict__ dt_b, const float* __restrict__ A_log,
    const float* __restrict__ Dp, u16* __restrict__ yb)
{
    __shared__ __align__(16) char smem[54528];
    u16*   xcy  = (u16*)smem;                    // [16][1032]          33024 B
    float* pxp  = (float*)(smem + 33024);        // [2][16][64] f32      8192 B
    u16*   dtH  = (u16*)(smem + 33024);          // [16][512] bf16 (alias, 16384 B)
    float* dbcL = (float*)(smem + 49408);        // [16][64]             4096 B
    u16*   dtiL = (u16*)(smem + 53504);          // [16][32]             1024 B

    const int tid  = threadIdx.x;
    const int lane = tid & 63;
    const int wv   = tid >> 6;                   // 0..7
    const int bc   = blockIdx.x >> 1;
    const int half = blockIdx.x & 1;
    const size_t rbase = (size_t)bc * L_;

    const int frow = lane & 15;
    const int fkg  = (lane >> 4) * 8;

    // ---- stage xc tile [16][1024] -> LDS (64B per thread)
    {
        int r = tid >> 5, c = (tid & 31) * 32;
        const u16* src = xcb + (rbase + r) * DI_ + c;
#pragma unroll
        for (int q = 0; q < 4; ++q)
            *(u16x8*)&xcy[r * XST + c + q * 8] = *(const u16x8*)(src + q * 8);
    }
    __syncthreads();

    // ---- x-proj: dbc[16,64] = xc[16,1024] x xproj_w[64,1024]^T
    // wave wv: ef = wv&3 (16-col frag), K-slice = wv>>2 (512 wide)
    {
        const int ef = wv & 3, sl = wv >> 2;
        f32x4 xacc = {};
#pragma unroll
        for (int kf = 0; kf < 16; ++kf) {
            int k = sl * 512 + kf * 32 + fkg;
            bf16x8 a = *(const bf16x8*)&xcy[frow * XST + k];
            bf16x8 b = *(const bf16x8*)&xp_wb[(size_t)(ef * 16 + frow) * DI_ + k];
            xacc = MFMA16(a, b, xacc);
        }
#pragma unroll
        for (int j = 0; j < 4; ++j)
            pxp[sl * 1024 + ((lane >> 4) * 4 + j) * 64 + ef * 16 + frow] = xacc[j];
    }
    __syncthreads();

    // ---- reduce 2 partials -> dbcL f32 + dtiL bf16
    {
        int e = tid & 63;
#pragma unroll
        for (int li = 0; li < 2; ++li) {
            int l = (tid >> 6) * 2 + li;
            float v = pxp[l * 64 + e] + pxp[1024 + l * 64 + e];
            dbcL[l * 64 + e] = v;
            if (e < DT_) dtiL[l * DT_ + e] = f2bf(v);
        }
    }
    __syncthreads();

    // ---- dt-proj for this half: d = half*512 + wv*64 + nf*16 + frow
    {
        bf16x8 a = *(const bf16x8*)&dtiL[frow * DT_ + fkg];
#pragma unroll
        for (int nf = 0; nf < 4; ++nf) {
            int dl = wv * 64 + nf * 16 + frow;      // local d (0..511)
            int d  = half * 512 + dl;
            bf16x8 b = *(const bf16x8*)&dt_wb[(size_t)d * DT_ + fkg];
            f32x4 c = {};
            c = MFMA16(a, b, c);
            float dtb = dt_b[d];
#pragma unroll
            for (int j = 0; j < 4; ++j) {
                int l = (lane >> 4) * 4 + j;
                float din = c[j] + dtb;
                float dtv = (din > 20.f) ? din : __logf(1.f + __expf(din));
                dtH[l * 512 + dl] = f2bf(dtv);
            }
        }
    }
    __syncthreads();

    // ---- scan: thread d = half*512 + tid
    {
        const int d = half * 512 + tid;
        float Arow[DS_];
        {
            float4 a0 = *(const float4*)&A_log[d * DS_ + 0];
            float4 a1 = *(const float4*)&A_log[d * DS_ + 4];
            float4 a2 = *(const float4*)&A_log[d * DS_ + 8];
            float4 a3 = *(const float4*)&A_log[d * DS_ + 12];
            Arow[0] = -__expf(a0.x); Arow[1] = -__expf(a0.y);
            Arow[2] = -__expf(a0.z); Arow[3] = -__expf(a0.w);
            Arow[4] = -__expf(a1.x); Arow[5] = -__expf(a1.y);
            Arow[6] = -__expf(a1.z); Arow[7] = -__expf(a1.w);
            Arow[8] = -__expf(a2.x); Arow[9] = -__expf(a2.y);
            Arow[10] = -__expf(a2.z); Arow[11] = -__expf(a2.w);
            Arow[12] = -__expf(a3.x); Arow[13] = -__expf(a3.y);
            Arow[14] = -__expf(a3.z); Arow[15] = -__expf(a3.w);
        }
        float Dpd = Dp[d];
        float st[DS_];
#pragma unroll
        for (int s = 0; s < DS_; ++s) st[s] = 0.f;
        const u16* srp = sresb + rbase * DI_ + d;
        u16* yp = yb + rbase * DI_ + d;
        for (int l = 0; l < L_; ++l) {
            float dtv = bf2f(dtH[l * 512 + tid]);
            float u = bf2f(xcy[l * XST + d]);
            float du = dtv * u;
            float y = 0.f;
#pragma unroll
            for (int s = 0; s < DS_; ++s) {
                float dA = __expf(dtv * Arow[s]);
                st[s] = dA * st[s] + du * dbcL[l * 64 + DT_ + s];
                y += st[s] * dbcL[l * 64 + DT_ + DS_ + s];
            }
            float sres = bf2f(srp[(size_t)l * DI_]);
            yp[(size_t)l * DI_] = f2bf((y + Dpd * u) * sres);
        }
    }
}

// ---------------------------------------------------------------------------
// Residual add (h + updb0 + updb1 + out_b) + joint LayerNorm over (L,D).
// upd partials are bf16.
// ---------------------------------------------------------------------------
__global__ __launch_bounds__(256) void ln_kernel(
    float* __restrict__ h, const u16* __restrict__ updb,
    const float* __restrict__ out_b,
    const float* __restrict__ ln_w, const float* __restrict__ ln_b,
    u16* __restrict__ hb)
{
    int bc = blockIdx.x;
    int tid = threadIdx.x;
    __shared__ float vbuf[L_ * D_];   // 32 KiB
    __shared__ float ps[4];
    __shared__ float mu_s, rstd_s;

    float4* vb4 = (float4*)vbuf;
    const float4* h4 = (const float4*)(h + (size_t)bc * 8192);
    const u16* u0 = updb + (size_t)bc * 8192;
    const u16* u1 = updb + (size_t)2097152 + (size_t)bc * 8192;
    const float4* ob = (const float4*)out_b;

    float s = 0.f;
    for (int j = tid; j < 2048; j += 256) {
        float4 v = h4[j], o = ob[j & 127];
        u16x4 a = *(const u16x4*)(u0 + j * 4);
        u16x4 b = *(const u16x4*)(u1 + j * 4);
        v.x += bf2f(a[0]) + bf2f(b[0]) + o.x;
        v.y += bf2f(a[1]) + bf2f(b[1]) + o.y;
        v.z += bf2f(a[2]) + bf2f(b[2]) + o.z;
        v.w += bf2f(a[3]) + bf2f(b[3]) + o.w;
        vb4[j] = v;
        s += v.x + v.y + v.z + v.w;
    }
#pragma unroll
    for (int o = 32; o > 0; o >>= 1) s += __shfl_down(s, o);
    if ((tid & 63) == 0) ps[tid >> 6] = s;
    __syncthreads();
    if (tid == 0) mu_s = (ps[0] + ps[1] + ps[2] + ps[3]) * (1.f / 8192.f);
    __syncthreads();
    float mu = mu_s;

    float s2 = 0.f;
    for (int j = tid; j < 8192; j += 256) {
        float v = vbuf[j] - mu;
        s2 += v * v;
    }
#pragma unroll
    for (int o = 32; o > 0; o >>= 1) s2 += __shfl_down(s2, o);
    if ((tid & 63) == 0) ps[tid >> 6] = s2;
    __syncthreads();
    if (tid == 0) rstd_s = rsqrtf((ps[0] + ps[1] + ps[2] + ps[3]) * (1.f / 8192.f) + EPS_);
    __syncthreads();
    float rstd = rstd_s;

    const float4* lw4 = (const float4*)ln_w;
    const float4* lb4 = (const float4*)ln_b;
    float4* ho4 = (float4*)(h + (size_t)bc * 8192);
    for (int j = tid; j < 2048; j += 256) {
        float4 v = vb4[j], w = lw4[j], b = lb4[j];
        v.x = (v.x - mu) * rstd * w.x + b.x;
        v.y = (v.y - mu) * rstd * w.y + b.y;
        v.z = (v.z - mu) * rstd * w.z + b.z;
        v.w = (v.w - mu) * rstd * w.w + b.w;
        ho4[j] = v;
        u16x4 ob16; ob16[0] = f2bf(v.x); ob16[1] = f2bf(v.y);
        ob16[2] = f2bf(v.z); ob16[3] = f2bf(v.w);
        *(u16x4*)&hb[(size_t)bc * 8192 + j * 4] = ob16;
    }
}

// out[b,s,c] = step_b[s] + sum_ks part[ks, b*CN+c, s]   (32 slices)
__global__ __launch_bounds__(256) void head_reduce_kernel(
    const float* __restrict__ part, const float* __restrict__ step_b,
    float* __restrict__ out)
{
    int j = blockIdx.x * 256 + threadIdx.x;  // (b*S+s)*CN + c
    int c = j & (CN_ - 1);
    int bs = j >> 7;
    int s = bs & (S_ - 1);
    int b = bs >> 8;
    int m = b * CN_ + c;
    float acc = step_b[s];
#pragma unroll
    for (int ks = 0; ks < 32; ++ks) acc += part[((size_t)ks * 256 + m) * 256 + s];
    out[j] = acc;
}

// ---------------------------------------------------------------------------
extern "C" void kernel_launch(void* const* d_in, const int* in_sizes, int n_in,
                              void* d_out, int out_size, void* d_ws, size_t ws_size,
                              hipStream_t stream)
{
    const float* x      = (const float*)d_in[0];
    const float* emb_w  = (const float*)d_in[1];
    const float* emb_b  = (const float*)d_in[2];
    const float* in_w   = (const float*)d_in[3];
    const float* in_b   = (const float*)d_in[4];
    const float* conv_w = (const float*)d_in[5];
    const float* conv_b = (const float*)d_in[6];
    const float* xproj_w= (const float*)d_in[7];
    const float* dt_w   = (const float*)d_in[8];
    const float* dt_b   = (const float*)d_in[9];
    const float* A_log  = (const float*)d_in[10];
    const float* Dp     = (const float*)d_in[11];
    const float* out_w  = (const float*)d_in[12];
    const float* out_b  = (const float*)d_in[13];
    const float* ln_w   = (const float*)d_in[14];
    const float* ln_b   = (const float*)d_in[15];
    const float* step_w = (const float*)d_in[16];
    const float* step_b = (const float*)d_in[17];
    float* out = (float*)d_out;

    char* ws = (char*)d_ws;
    float* h     = (float*)(ws);                    //  8 MiB [4096,512]
    u16*   hb    = (u16*)  (ws + 8388608);          //  4 MiB
    u16*   xcb   = (u16*)  (ws + 12582912);         //  8 MiB [4096,1024]
    u16*   sresb = (u16*)  (ws + 20971520);         //  8 MiB
    u16*   yb    = (u16*)  (ws + 29360128);         //  8 MiB
    u16*   updb  = (u16*)  (ws + 37748736);         //  8 MiB [2][4096][512] bf16
    u16*   in_wb = (u16*)  (ws + 46137344);         //  8 MiB
    u16*   out_wb= (u16*)  (ws + 54525952);         //  4 MiB
    u16*   xp_wb = (u16*)  (ws + 58720256);         //  0.5 MiB
    u16*   st_wb = (u16*)  (ws + 59244544);         //  4 MiB
    u16*   dt_wb = (u16*)  (ws + 63438848);         //  0.25 MiB
    float* part  = (float*)(ws + 63700992);         //  8 MiB [32,256,256]

    const int M = B_ * CN_ * L_;  // 4096

    cvt_all<<<4288, 256, 0, stream>>>(in_w, out_w, xproj_w, step_w, dt_w,
                                      in_wb, out_wb, xp_wb, st_wb, dt_wb);
    embed_kernel<<<M, 256, 0, stream>>>(x, emb_w, emb_b, h, hb);

    for (int i = 0; i < NB_; ++i) {
        // in-proj + bias + causal conv + silu + res-silu (fused epilogue)
        gemm_bf16<1><<<dim3(M / 128, 16, 1), 256, 0, stream>>>(
            hb, D_, in_wb + (size_t)i * 2 * DI_ * D_, D_,
            nullptr, 0, 2 * DI_, D_ / 32, 0, 0,
            in_b + (size_t)i * 2 * DI_, conv_w + (size_t)i * DI_ * DC_,
            conv_b + (size_t)i * DI_, xcb, sresb);
        // x-proj + dt-proj + scan + gate -> yb (512 blocks, 2 per (b,c))
        scanf_kernel<<<B_ * CN_ * 2, 512, 0, stream>>>(
            xcb, sresb,
            xp_wb + (size_t)i * 64 * DI_, dt_wb + (size_t)i * DI_ * DT_,
            dt_b + (size_t)i * DI_, A_log + (size_t)i * DI_ * DS_,
            Dp + (size_t)i * DI_, yb);
        // out-proj split-K x2 -> updb bf16 partials
        gemm_bf16<2><<<dim3(M / 128, 4, 2), 256, 0, stream>>>(
            yb, DI_, out_wb + (size_t)i * D_ * DI_, DI_,
            (float*)updb, D_, D_, 16, 512, M * D_,
            nullptr, nullptr, nullptr, nullptr, nullptr);
        // residual (+out_b) + LayerNorm
        ln_kernel<<<B_ * CN_, 256, 0, stream>>>(
            h, updb, out_b + (size_t)i * D_,
            ln_w + (size_t)i * L_ * D_, ln_b + (size_t)i * L_ * D_, hb);
    }

    // head: split-K 32 MFMA GEMM + reduce/transpose
    gemm_bf16<0><<<dim3(2, 2, 32), 256, 0, stream>>>(
        hb, L_ * D_, st_wb, L_ * D_,
        part, S_, S_, 8, 256, 256 * 256,
        nullptr, nullptr, nullptr, nullptr, nullptr);
    head_reduce_kernel<<<(B_ * S_ * CN_) / 256, 256, 0, stream>>>(part, step_b, out);
}